// Round 8
// baseline (417.661 us; speedup 1.0000x reference)
//
#include <hip/hip_runtime.h>
#include <hip/hip_bf16.h>
#include <math.h>

#define NJ 30000
#define NS 12000
#define E_JS 300000
#define E_SJ 300000
#define E_SS 150000
#define ETOT (E_JS + E_SJ + E_SS + NS)   // 762000 incl. ss self loops
#define NBINS (NS + NJ + NS)             // 54000 combined dst bins
#define NBUK ((NBINS + 63) / 64)         // 844 coarse buckets (64 bins each)
#define SBERT 384
#define HIST_NB 512                      // 256-thr hist blocks
#define SCAT_NB 120                      // 256-thr scatter blocks

static inline int cdiv(int a, int b) { return (a + b - 1) / b; }

typedef __attribute__((ext_vector_type(8))) short bf8_t;
typedef __attribute__((ext_vector_type(4))) float f4_t;
typedef unsigned short u16;

__device__ inline float bf2f(unsigned short u) {
    union { unsigned int i; float f; } z; z.i = ((unsigned int)u) << 16; return z.f;
}
__device__ inline unsigned short f2bf(float f) {
    unsigned int x = __float_as_uint(f);
    unsigned int r = (x + 0x7fffu + ((x >> 16) & 1u)) >> 16;   // RNE
    return (unsigned short)r;
}

// ---------------------------------------------------------------------------
// edge decode for combined CSR
// bin layout: [0,NS) js | [NS,NS+NJ) sj | [NS+NJ,NBINS) ss (incl self loops)
// ---------------------------------------------------------------------------
__device__ inline void edge_decode(int e, const int* js_src, const int* js_dst,
                                   const int* sj_src, const int* sj_dst,
                                   const int* ss_src, const int* ss_dst,
                                   int& src, int& bin) {
    if (e < E_JS) { src = js_src[e]; bin = js_dst[e]; }
    else if (e < E_JS + E_SJ) { int i = e - E_JS; src = sj_src[i]; bin = NS + sj_dst[i]; }
    else if (e < E_JS + E_SJ + E_SS) { int i = e - E_JS - E_SJ; src = ss_src[i]; bin = NS + NJ + ss_dst[i]; }
    else { int i = e - E_JS - E_SJ - E_SS; src = i; bin = NS + NJ + i; }
}

// ---------------------------------------------------------------------------
// k_prep: (a) 13 weight transpose+casts, (b) wa precompute + bcnt zero,
// (c) qv = query @ Wq + bq.  blocks: [0,2496) castT [2496,2508) wa [2508] qvec
// ---------------------------------------------------------------------------
struct CastT { const float* src; unsigned short* dst; int K; int N; };
struct PrepArgs {
    CastT m[13];
    const float* Ws; const float* as_; const float* Wd; const float* ad_;
    float* wsa; float* wda; int* bcnt;
    const float* query; const float* Wq; const float* bq; float* qv;
};

__global__ __launch_bounds__(256) void k_prep(PrepArgs A) {
    int b = blockIdx.x;
    if (b < 2496) {
        int mi = b / 192, bx = b % 192;
        CastT c = A.m[mi];
        int idx = bx * 256 + threadIdx.x;
        if (idx < c.K * c.N) {
            int n = idx / c.K, k = idx % c.K;
            c.dst[idx] = f2bf(c.src[(size_t)k * c.N + n]);
        }
    } else if (b < 2508) {
        int id = (b - 2496) * 256 + threadIdx.x;
        if (id < NBUK) A.bcnt[id] = 0;
        if (id >= 2 * 1536) return;
        int which = id / 1536;
        int r = id % 1536;
        int lr = r / 256;
        int kh = r % 256;
        int k = kh / 2, h = kh % 2;
        const float* W = which ? A.Wd : A.Ws;
        const float* a = which ? A.ad_ : A.as_;
        const float* wrow = W + ((size_t)(lr * 128 + k)) * 256 + h * 128;
        const float* arow = a + (size_t)(lr * 2 + h) * 128;
        float acc = 0.f;
        for (int c2 = 0; c2 < 128; ++c2) acc += wrow[c2] * arow[c2];
        (which ? A.wda : A.wsa)[lr * 256 + k * 2 + h] = acc;
    } else {
        int c = threadIdx.x;
        if (c < 128) {
            float acc = A.bq[c];
            for (int k = 0; k < SBERT; ++k) acc += A.query[k] * A.Wq[(size_t)k * 128 + c];
            A.qv[c] = acc;
        }
    }
}

// ---------------------------------------------------------------------------
// MFMA GEMM body (device fn). BM=64, 4 waves x (16m x 128n).
//   EPI: 0 none->bf16, 1 +bias->fp32 +fused scores, 2 +bias,relu->bf16,
//        3 +bias,LN,relu->bf16.  srcf32: fp32 A converted during staging.
// ---------------------------------------------------------------------------
struct GJob {
    const void* X; const unsigned short* Wt;
    const float* bias; const float* gamma; const float* beta;
    void* Y; int M; int K; int N; int ldY; int srcf32;
    const float* qv; float* sc;
};
struct GPair { GJob a; GJob b; int blocksA; };

template <int EPI>
__device__ void mgemm_body(const GPair& P, int bx, int by) {
    int mb = bx;
    GJob g = (mb < P.blocksA) ? P.a : P.b;
    if (mb >= P.blocksA) mb -= P.blocksA;
    const int n0 = by * 128;
    if (n0 >= g.N) return;
    const int row0 = mb * 64;

    __shared__ __align__(16) unsigned short Al[64][40];
    __shared__ __align__(16) unsigned short Bl[128][40];
    const int t = threadIdx.x;
    const int wave = t >> 6, lane = t & 63;
    const int q = lane >> 4, c = lane & 15;
    const int K = g.K;

    f4_t acc[8];
#pragma unroll
    for (int nt = 0; nt < 8; ++nt) acc[nt] = (f4_t){0.f, 0.f, 0.f, 0.f};

    for (int k0 = 0; k0 < K; k0 += 32) {
#pragma unroll
        for (int it = 0; it < 3; ++it) {
            int idx = t + it * 256;
            int r = idx >> 2, cc = (idx & 3) * 8;
            if (r < 64) {
                int gr = row0 + r;
                if (g.srcf32) {
                    ushort4 lo = make_ushort4(0, 0, 0, 0), hi = lo;
                    if (gr < g.M) {
                        const float* Xf = (const float*)g.X;
                        const float* p = &Xf[(size_t)gr * K + k0 + cc];
                        float4 f0 = *(const float4*)p;
                        float4 f1 = *(const float4*)(p + 4);
                        lo = make_ushort4(f2bf(f0.x), f2bf(f0.y), f2bf(f0.z), f2bf(f0.w));
                        hi = make_ushort4(f2bf(f1.x), f2bf(f1.y), f2bf(f1.z), f2bf(f1.w));
                    }
                    *(ushort4*)&Al[r][cc] = lo;
                    *(ushort4*)&Al[r][cc + 4] = hi;
                } else {
                    const unsigned short* Xb = (const unsigned short*)g.X;
                    uint4 va = (gr < g.M) ? *(const uint4*)&Xb[(size_t)gr * K + k0 + cc]
                                          : make_uint4(0u, 0u, 0u, 0u);
                    *(uint4*)&Al[r][cc] = va;
                }
            } else {
                int br = r - 64;
                *(uint4*)&Bl[br][cc] = *(const uint4*)&g.Wt[(size_t)(n0 + br) * K + k0 + cc];
            }
        }
        __syncthreads();
        bf8_t af = *(const bf8_t*)&Al[wave * 16 + c][q * 8];
#pragma unroll
        for (int nt = 0; nt < 8; ++nt) {
            bf8_t bfr = *(const bf8_t*)&Bl[nt * 16 + c][q * 8];
            acc[nt] = __builtin_amdgcn_mfma_f32_16x16x32_bf16(af, bfr, acc[nt], 0, 0, 0);
        }
        __syncthreads();
    }

    float bcol[8], gcol[8], becol[8], qcol[8];
#pragma unroll
    for (int nt = 0; nt < 8; ++nt) {
        bcol[nt] = (EPI >= 1) ? g.bias[n0 + nt * 16 + c] : 0.f;
        if constexpr (EPI == 3) {
            gcol[nt] = g.gamma[nt * 16 + c];
            becol[nt] = g.beta[nt * 16 + c];
        }
        if constexpr (EPI == 1) qcol[nt] = g.qv[n0 + nt * 16 + c];
    }

#pragma unroll
    for (int r = 0; r < 4; ++r) {
        int grow = row0 + wave * 16 + q * 4 + r;
        float v[8];
#pragma unroll
        for (int nt = 0; nt < 8; ++nt) v[nt] = acc[nt][r] + bcol[nt];
        if constexpr (EPI == 3) {
            float s = 0.f, ss = 0.f;
#pragma unroll
            for (int nt = 0; nt < 8; ++nt) { s += v[nt]; ss += v[nt] * v[nt]; }
#pragma unroll
            for (int m = 8; m >= 1; m >>= 1) {
                s += __shfl_xor(s, m, 64);
                ss += __shfl_xor(ss, m, 64);
            }
            float mu = s * (1.f / 128.f);
            float var = ss * (1.f / 128.f) - mu * mu;
            float rs = rsqrtf(var + 1e-5f);
#pragma unroll
            for (int nt = 0; nt < 8; ++nt)
                v[nt] = fmaxf((v[nt] - mu) * rs * gcol[nt] + becol[nt], 0.f);
        } else if constexpr (EPI == 2) {
#pragma unroll
            for (int nt = 0; nt < 8; ++nt) v[nt] = fmaxf(v[nt], 0.f);
        }
        if constexpr (EPI == 1) {
            float part = 0.f;
#pragma unroll
            for (int nt = 0; nt < 8; ++nt) part += v[nt] * qcol[nt];
#pragma unroll
            for (int m = 8; m >= 1; m >>= 1) part += __shfl_xor(part, m, 64);
            if (c == 0 && grow < g.M) g.sc[grow] = part;
        }
        if (grow < g.M) {
            if constexpr (EPI == 1) {
                float* Y = (float*)g.Y;
#pragma unroll
                for (int nt = 0; nt < 8; ++nt)
                    Y[(size_t)grow * g.ldY + n0 + nt * 16 + c] = v[nt];
            } else {
                unsigned short* Y = (unsigned short*)g.Y;
#pragma unroll
                for (int nt = 0; nt < 8; ++nt)
                    Y[(size_t)grow * g.ldY + n0 + nt * 16 + c] = f2bf(v[nt]);
            }
        }
    }
}

template <int EPI>
__global__ __launch_bounds__(256) void k_mgemm(GPair P) {
    mgemm_body<EPI>(P, blockIdx.x, blockIdx.y);
}

// ---------------------------------------------------------------------------
// alpha body (device fn)
//   aJ[n][4] = {as_js(h0,h1), ad_sj(h0,h1)}
//   aS[n][8] = {as_ss(h0,h1), ad_js(h0,h1), as_sj(h0,h1), ad_ss(h0,h1)}
// ---------------------------------------------------------------------------
__device__ void alpha_body(const unsigned short* xj, const unsigned short* xs,
                           const float* wsa, const float* wda, int l3,
                           float* aJ, float* aS, int b) {
    int wave = threadIdx.x >> 6, lane = threadIdx.x & 63;
    int node = b * 4 + wave;
    if (node < NJ) {
        ushort2 xv = *(const ushort2*)&xj[(size_t)node * 128 + lane * 2];
        float x0 = bf2f(xv.x), x1 = bf2f(xv.y);
        float4 w0 = *(const float4*)&wsa[(size_t)(l3 + 0) * 256 + lane * 4];
        float4 w1 = *(const float4*)&wda[(size_t)(l3 + 1) * 256 + lane * 4];
        float p0 = x0 * w0.x + x1 * w0.z, p1 = x0 * w0.y + x1 * w0.w;
        float p2 = x0 * w1.x + x1 * w1.z, p3 = x0 * w1.y + x1 * w1.w;
#pragma unroll
        for (int m = 32; m >= 1; m >>= 1) {
            p0 += __shfl_xor(p0, m, 64); p1 += __shfl_xor(p1, m, 64);
            p2 += __shfl_xor(p2, m, 64); p3 += __shfl_xor(p3, m, 64);
        }
        if (lane == 0) *(float4*)&aJ[(size_t)node * 4] = make_float4(p0, p1, p2, p3);
    } else if (node < NJ + NS) {
        int n = node - NJ;
        ushort2 xv = *(const ushort2*)&xs[(size_t)n * 128 + lane * 2];
        float x0 = bf2f(xv.x), x1 = bf2f(xv.y);
        float4 wA = *(const float4*)&wsa[(size_t)(l3 + 2) * 256 + lane * 4];
        float4 wB = *(const float4*)&wda[(size_t)(l3 + 0) * 256 + lane * 4];
        float4 wC = *(const float4*)&wsa[(size_t)(l3 + 1) * 256 + lane * 4];
        float4 wD = *(const float4*)&wda[(size_t)(l3 + 2) * 256 + lane * 4];
        float p0 = x0 * wA.x + x1 * wA.z, p1 = x0 * wA.y + x1 * wA.w;
        float p2 = x0 * wB.x + x1 * wB.z, p3 = x0 * wB.y + x1 * wB.w;
        float p4 = x0 * wC.x + x1 * wC.z, p5 = x0 * wC.y + x1 * wC.w;
        float p6 = x0 * wD.x + x1 * wD.z, p7 = x0 * wD.y + x1 * wD.w;
#pragma unroll
        for (int m = 32; m >= 1; m >>= 1) {
            p0 += __shfl_xor(p0, m, 64); p1 += __shfl_xor(p1, m, 64);
            p2 += __shfl_xor(p2, m, 64); p3 += __shfl_xor(p3, m, 64);
            p4 += __shfl_xor(p4, m, 64); p5 += __shfl_xor(p5, m, 64);
            p6 += __shfl_xor(p6, m, 64); p7 += __shfl_xor(p7, m, 64);
        }
        if (lane == 0) {
            float4* o = (float4*)&aS[(size_t)n * 8];
            o[0] = make_float4(p0, p1, p2, p3);
            o[1] = make_float4(p4, p5, p6, p7);
        }
    }
}

// ---------------------------------------------------------------------------
// D2: lin0 GEMM + bucket hist (merged)
// ---------------------------------------------------------------------------
__global__ __launch_bounds__(256) void k_lin0_hist(
    GPair P, int gemmBlocks,
    const int* __restrict__ js_src, const int* __restrict__ js_dst,
    const int* __restrict__ sj_src, const int* __restrict__ sj_dst,
    const int* __restrict__ ss_src, const int* __restrict__ ss_dst,
    int* __restrict__ bcnt) {
    if (blockIdx.x < (unsigned)gemmBlocks) {
        mgemm_body<3>(P, blockIdx.x, blockIdx.y);
        return;
    }
    // hist path
    __shared__ int lh[NBUK];
    int t = threadIdx.x;
    for (int i = t; i < NBUK; i += 256) lh[i] = 0;
    __syncthreads();
    int hb = blockIdx.x - gemmBlocks;
    for (int e = hb * 256 + t; e < ETOT; e += HIST_NB * 256) {
        int src, bin;
        edge_decode(e, js_src, js_dst, sj_src, sj_dst, ss_src, ss_dst, src, bin);
        atomicAdd(&lh[bin >> 6], 1);
    }
    __syncthreads();
    for (int i = t; i < NBUK; i += 256) {
        int v = lh[i];
        if (v) atomicAdd(&bcnt[i], v);
    }
}

// ---------------------------------------------------------------------------
// D3: alpha(l0) + bucket scan (merged). scan block = last block, 256 thr,
// 4 elems/thread over NBUK=844.
// ---------------------------------------------------------------------------
__global__ __launch_bounds__(256) void k_alpha_scan(
    const unsigned short* __restrict__ xj, const unsigned short* __restrict__ xs,
    const float* __restrict__ wsa, const float* __restrict__ wda, int l3,
    float* __restrict__ aJ, float* __restrict__ aS, int alphaBlocks,
    const int* __restrict__ bcnt, int* __restrict__ bukoff, int* __restrict__ bukcur) {
    if (blockIdx.x < (unsigned)alphaBlocks) {
        alpha_body(xj, xs, wsa, wda, l3, aJ, aS, blockIdx.x);
        return;
    }
    // scan path
    __shared__ int sd[256];
    int t = threadIdx.x;
    int i0 = t * 4;
    int v0 = (i0 < NBUK) ? bcnt[i0] : 0;
    int v1 = (i0 + 1 < NBUK) ? bcnt[i0 + 1] : 0;
    int v2 = (i0 + 2 < NBUK) ? bcnt[i0 + 2] : 0;
    int v3 = (i0 + 3 < NBUK) ? bcnt[i0 + 3] : 0;
    int csum = v0 + v1 + v2 + v3;
    sd[t] = csum;
    __syncthreads();
    for (int off = 1; off < 256; off <<= 1) {
        int tmp = (t >= off) ? sd[t - off] : 0;
        __syncthreads();
        sd[t] += tmp;
        __syncthreads();
    }
    int excl = sd[t] - csum;
    int p0 = excl, p1 = excl + v0, p2 = excl + v0 + v1, p3 = excl + v0 + v1 + v2;
    if (i0 < NBUK) { bukoff[i0] = p0; bukcur[i0] = p0; }
    if (i0 + 1 < NBUK) { bukoff[i0 + 1] = p1; bukcur[i0 + 1] = p1; }
    if (i0 + 2 < NBUK) { bukoff[i0 + 2] = p2; bukcur[i0 + 2] = p2; }
    if (i0 + 3 < NBUK) { bukoff[i0 + 3] = p3; bukcur[i0 + 3] = p3; }
    if (t == 0) bukoff[NBUK] = ETOT;
}

// ---------------------------------------------------------------------------
// D4: scatter pairs (256-thr LDS-aggregated) + proj GEMM l0 (merged)
// ---------------------------------------------------------------------------
__global__ __launch_bounds__(256) void k_scatter_proj(
    GPair P, int gemmBlocks,
    const int* __restrict__ js_src, const int* __restrict__ js_dst,
    const int* __restrict__ sj_src, const int* __restrict__ sj_dst,
    const int* __restrict__ ss_src, const int* __restrict__ ss_dst,
    int* __restrict__ bukcur, uint2* __restrict__ pairs) {
    if (blockIdx.x < (unsigned)gemmBlocks) {
        mgemm_body<0>(P, blockIdx.x, blockIdx.y);
        return;
    }
    if (blockIdx.y != 0) return;
    __shared__ int lh[NBUK];
    __shared__ int lbase[NBUK];
    int t = threadIdx.x;
    int sb = blockIdx.x - gemmBlocks;
    const int CH = (ETOT + SCAT_NB - 1) / SCAT_NB;
    const int beg = sb * CH;
    const int endi = (beg + CH < ETOT) ? beg + CH : ETOT;
    for (int i = t; i < NBUK; i += 256) lh[i] = 0;
    __syncthreads();
    for (int e = beg + t; e < endi; e += 256) {
        int src, bin;
        edge_decode(e, js_src, js_dst, sj_src, sj_dst, ss_src, ss_dst, src, bin);
        atomicAdd(&lh[bin >> 6], 1);
    }
    __syncthreads();
    for (int i = t; i < NBUK; i += 256) {
        int v = lh[i];
        lbase[i] = v ? atomicAdd(&bukcur[i], v) : 0;
    }
    __syncthreads();
    for (int i = t; i < NBUK; i += 256) lh[i] = 0;
    __syncthreads();
    for (int e = beg + t; e < endi; e += 256) {
        int src, bin;
        edge_decode(e, js_src, js_dst, sj_src, sj_dst, ss_src, ss_dst, src, bin);
        int bu = bin >> 6;
        int pos = lbase[bu] + atomicAdd(&lh[bu], 1);
        pairs[pos] = make_uint2((unsigned)src, (unsigned)bin);
    }
}

// ---------------------------------------------------------------------------
// D8: proj GEMM l1 + alpha(l1) (merged)
// ---------------------------------------------------------------------------
__global__ __launch_bounds__(256) void k_proj_alpha(
    GPair P, int gemmBlocks,
    const unsigned short* __restrict__ xj, const unsigned short* __restrict__ xs,
    const float* __restrict__ wsa, const float* __restrict__ wda, int l3,
    float* __restrict__ aJ, float* __restrict__ aS) {
    if (blockIdx.x < (unsigned)gemmBlocks) {
        mgemm_body<0>(P, blockIdx.x, blockIdx.y);
        return;
    }
    if (blockIdx.y != 0) return;
    alpha_body(xj, xs, wsa, wda, l3, aJ, aS, blockIdx.x - gemmBlocks);
}

// ---------------------------------------------------------------------------
// finalize: one block per bucket, dense contiguous esrc writes
// ---------------------------------------------------------------------------
__global__ __launch_bounds__(256) void k_finalize(
    const uint2* __restrict__ pairs, const int* __restrict__ bukoff,
    int* __restrict__ offs, int* __restrict__ esrc) {
    int b = blockIdx.x, t = threadIdx.x;
    int base = bukoff[b], endi = bukoff[b + 1];
    __shared__ int cnt[64], excl[64], curs[64];
    if (t < 64) cnt[t] = 0;
    __syncthreads();
    for (int i = base + t; i < endi; i += 256)
        atomicAdd(&cnt[pairs[i].y & 63], 1);
    __syncthreads();
    if (t < 64) {
        int v = cnt[t];
        int inc = v;
#pragma unroll
        for (int off = 1; off < 64; off <<= 1) {
            int tmp = __shfl_up(inc, off, 64);
            if (t >= off) inc += tmp;
        }
        excl[t] = inc - v;
        curs[t] = inc - v;
    }
    __syncthreads();
    for (int i = base + t; i < endi; i += 256) {
        uint2 p = pairs[i];
        int lb = p.y & 63;
        int pos = atomicAdd(&curs[lb], 1);
        esrc[base + pos] = (int)p.x;
    }
    if (t < 64) {
        int bin = b * 64 + t;
        if (bin < NBINS) offs[bin] = base + excl[t];
    }
    if (b == 0 && t == 0) offs[NBINS] = ETOT;
}

// ---------------------------------------------------------------------------
// Combined gather for one layer, 8-way unrolled edge loop (clamped tail).
// ---------------------------------------------------------------------------
__device__ inline void edge_accum(
    const int* __restrict__ esrc, int beg, int endi,
    const float* __restrict__ aSrc, int sStride, int hOff, float ad,
    const unsigned short* __restrict__ hs, int hsLd, int c,
    float& ax, float& ay, float& az, float& aw, float& den) {
    for (int j = beg; j < endi; j += 8) {
        int s[8]; float as[8]; ushort4 v[8];
#pragma unroll
        for (int i = 0; i < 8; ++i) {
            int jj = j + i < endi ? j + i : endi - 1;
            s[i] = esrc[jj];
        }
#pragma unroll
        for (int i = 0; i < 8; ++i) as[i] = aSrc[(size_t)s[i] * sStride + hOff];
#pragma unroll
        for (int i = 0; i < 8; ++i) v[i] = *(const ushort4*)&hs[(size_t)s[i] * hsLd + c];
#pragma unroll
        for (int i = 0; i < 8; ++i) {
            float e = as[i] + ad;
            e = e > 0.f ? e : 0.2f * e;
            float p = (j + i < endi) ? __expf(e) : 0.f;
            ax += p * bf2f(v[i].x); ay += p * bf2f(v[i].y);
            az += p * bf2f(v[i].z); aw += p * bf2f(v[i].w);
            den += p;
        }
    }
}

__global__ __launch_bounds__(256) void k_gather_all(
    const int* __restrict__ offs, const int* __restrict__ esrc,
    const float* __restrict__ aJ, const float* __restrict__ aS,
    const unsigned short* __restrict__ hs1, const unsigned short* __restrict__ hs2,
    const float* __restrict__ gb,     // gat_b + l3*256
    unsigned short* __restrict__ oj, unsigned short* __restrict__ os) {
    int wave = threadIdx.x >> 6, lane = threadIdx.x & 63;
    int idx = blockIdx.x * 4 + wave;
    int c = lane * 4;
    int h = (c >= 128) ? 1 : 0;
    if (idx < NS) {
        int d = idx;
        float axA = 0.f, ayA = 0.f, azA = 0.f, awA = 0.f, denA = 0.f;
        edge_accum(esrc, offs[d], offs[d + 1], aJ, 4, h, aS[(size_t)d * 8 + 2 + h],
                   hs1, 256, c, axA, ayA, azA, awA, denA);
        float axB = 0.f, ayB = 0.f, azB = 0.f, awB = 0.f, denB = 0.f;
        int bb = NS + NJ + d;
        edge_accum(esrc, offs[bb], offs[bb + 1], aS, 8, h, aS[(size_t)d * 8 + 6 + h],
                   hs2 + 256, 512, c, axB, ayB, azB, awB, denB);
        float scA = 1.f / (denA + 1e-16f);
        float scB = 1.f / (denB + 1e-16f);
        float4 bA = *(const float4*)&gb[c];
        float4 bB = *(const float4*)&gb[512 + c];
        float o0 = axA * scA + bA.x + axB * scB + bB.x;
        float o1 = ayA * scA + bA.y + ayB * scB + bB.y;
        float o2 = azA * scA + bA.z + azB * scB + bB.z;
        float o3 = awA * scA + bA.w + awB * scB + bB.w;
        ushort4 o; o.x = f2bf(o0); o.y = f2bf(o1); o.z = f2bf(o2); o.w = f2bf(o3);
        *(ushort4*)&os[(size_t)d * 256 + c] = o;
    } else if (idx < NS + NJ) {
        int d = idx - NS;
        float ax = 0.f, ay = 0.f, az = 0.f, aw = 0.f, den = 0.f;
        int bb = NS + d;
        edge_accum(esrc, offs[bb], offs[bb + 1], aS, 8, 4 + h, aJ[(size_t)d * 4 + 2 + h],
                   hs2, 512, c, ax, ay, az, aw, den);
        float sc = 1.f / (den + 1e-16f);
        float4 b4 = *(const float4*)&gb[256 + c];
        float o0 = ax * sc + b4.x, o1 = ay * sc + b4.y;
        float o2 = az * sc + b4.z, o3 = aw * sc + b4.w;
        ushort4 o; o.x = f2bf(o0); o.y = f2bf(o1); o.z = f2bf(o2); o.w = f2bf(o3);
        *(ushort4*)&oj[(size_t)d * 256 + c] = o;
    }
}

// ---------------------------------------------------------------------------
extern "C" void kernel_launch(void* const* d_in, const int* in_sizes, int n_in,
                              void* d_out, int out_size, void* d_ws, size_t ws_size,
                              hipStream_t stream) {
    const float* x_job   = (const float*)d_in[0];
    const float* x_skill = (const float*)d_in[1];
    const int* js_src = (const int*)d_in[2];
    const int* js_dst = (const int*)d_in[3];
    const int* sj_src = (const int*)d_in[4];
    const int* sj_dst = (const int*)d_in[5];
    const int* ss_src = (const int*)d_in[6];
    const int* ss_dst = (const int*)d_in[7];
    const float* query    = (const float*)d_in[8];
    const float* W0_job   = (const float*)d_in[9];
    const float* b0_job   = (const float*)d_in[10];
    const float* g0_job   = (const float*)d_in[11];
    const float* be0_job  = (const float*)d_in[12];
    const float* W0_skill = (const float*)d_in[13];
    const float* b0_skill = (const float*)d_in[14];
    const float* g0_skill = (const float*)d_in[15];
    const float* be0_skill= (const float*)d_in[16];
    const float* gat_Ws = (const float*)d_in[17];
    const float* gat_Wd = (const float*)d_in[18];
    const float* gat_as = (const float*)d_in[19];
    const float* gat_ad = (const float*)d_in[20];
    const float* gat_b  = (const float*)d_in[21];
    const float* inter_W = (const float*)d_in[22];
    const float* inter_b = (const float*)d_in[23];
    const float* Wjf = (const float*)d_in[24];
    const float* bjf = (const float*)d_in[25];
    const float* Wq  = (const float*)d_in[26];
    const float* bq  = (const float*)d_in[27];

    char* w = (char*)d_ws;
    auto alloc = [&](size_t bytes) -> void* {
        void* p = (void*)w;
        w += (bytes + 255) & ~(size_t)255;
        return p;
    };
    u16* xj  = (u16*)alloc((size_t)NJ * 128 * 2);
    u16* xs  = (u16*)alloc((size_t)NS * 128 * 2);
    u16* hs1 = (u16*)alloc((size_t)NJ * 256 * 2);
    u16* hs2 = (u16*)alloc((size_t)NS * 512 * 2);
    u16* oj  = (u16*)alloc((size_t)NJ * 256 * 2);
    u16* os  = (u16*)alloc((size_t)NS * 256 * 2);
    u16* WtW0j = (u16*)alloc((size_t)SBERT * 128 * 2);
    u16* WtW0s = (u16*)alloc((size_t)SBERT * 128 * 2);
    u16* WtWs  = (u16*)alloc((size_t)6 * 128 * 256 * 2);
    u16* WtI   = (u16*)alloc((size_t)4 * 256 * 128 * 2);
    u16* WtJf  = (u16*)alloc((size_t)128 * 128 * 2);
    float* aJ = (float*)alloc((size_t)NJ * 4 * 4);
    float* aS = (float*)alloc((size_t)NS * 8 * 4);
    float* wsa = (float*)alloc(6 * 256 * 4);
    float* wda = (float*)alloc(6 * 256 * 4);
    int* bcnt   = (int*)alloc((size_t)NBUK * 4);
    int* bukoff = (int*)alloc((size_t)(NBUK + 1) * 4);
    int* bukcur = (int*)alloc((size_t)NBUK * 4);
    uint2* pairs = (uint2*)alloc((size_t)ETOT * 8);
    int* offs = (int*)alloc((size_t)(NBINS + 1) * 4);
    int* esrc = (int*)alloc((size_t)ETOT * 4);

    float* out = (float*)d_out;
    float* scores  = out;
    float* job_emb = out + NJ;
    float* qv      = out + NJ + (size_t)NJ * 128;

    const int mbJ = cdiv(NJ, 64);   // 469
    const int mbS = cdiv(NS, 64);   // 188
    const int gemmB = mbJ + mbS;    // 657
    const int alphaB = cdiv(NJ + NS, 4);   // 10500

    // D1: prep
    {
        PrepArgs A;
        A.m[0] = {W0_job, WtW0j, SBERT, 128};
        A.m[1] = {W0_skill, WtW0s, SBERT, 128};
        for (int lr = 0; lr < 6; ++lr)
            A.m[2 + lr] = {gat_Ws + (size_t)lr * 128 * 256, WtWs + (size_t)lr * 256 * 128, 128, 256};
        for (int i = 0; i < 4; ++i)
            A.m[8 + i] = {inter_W + (size_t)i * 256 * 128, WtI + (size_t)i * 128 * 256, 256, 128};
        A.m[12] = {Wjf, WtJf, 128, 128};
        A.Ws = gat_Ws; A.as_ = gat_as; A.Wd = gat_Wd; A.ad_ = gat_ad;
        A.wsa = wsa; A.wda = wda; A.bcnt = bcnt;
        A.query = query; A.Wq = Wq; A.bq = bq; A.qv = qv;
        k_prep<<<2509, 256, 0, stream>>>(A);
    }

    // D2: lin0 (LN epilogue, fp32 src) + bucket hist
    {
        GPair P;
        P.a = {x_job, WtW0j, b0_job, g0_job, be0_job, xj, NJ, SBERT, 128, 128, 1, nullptr, nullptr};
        P.b = {x_skill, WtW0s, b0_skill, g0_skill, be0_skill, xs, NS, SBERT, 128, 128, 1, nullptr, nullptr};
        P.blocksA = mbJ;
        k_lin0_hist<<<dim3(gemmB + HIST_NB, 1), 256, 0, stream>>>(
            P, gemmB, js_src, js_dst, sj_src, sj_dst, ss_src, ss_dst, bcnt);
    }

    // D3: alpha(l0) + bucket scan
    k_alpha_scan<<<alphaB + 1, 256, 0, stream>>>(xj, xs, wsa, wda, 0, aJ, aS,
                                                 alphaB, bcnt, bukoff, bukcur);

    // D4: scatter pairs + proj GEMM l0
    {
        GPair P;
        P.a = {xj, WtWs + (size_t)0 * 256 * 128, nullptr, nullptr, nullptr,
               hs1, NJ, 128, 256, 256, 0, nullptr, nullptr};
        P.b = {xs, WtWs + (size_t)1 * 256 * 128, nullptr, nullptr, nullptr,
               hs2, NS, 128, 512, 512, 0, nullptr, nullptr};
        P.blocksA = mbJ;
        k_scatter_proj<<<dim3(gemmB + SCAT_NB, 4), 256, 0, stream>>>(
            P, gemmB, js_src, js_dst, sj_src, sj_dst, ss_src, ss_dst, bukcur, pairs);
    }

    // D5: finalize CSR
    k_finalize<<<NBUK, 256, 0, stream>>>(pairs, bukoff, offs, esrc);

    // D6: gather l0
    k_gather_all<<<cdiv(NS + NJ, 4), 256, 0, stream>>>(
        offs, esrc, aJ, aS, hs1, hs2, gat_b + 0, oj, os);

    // D7: inter l0
    {
        GPair P;
        P.a = {oj, WtI + (size_t)0 * 128 * 256, inter_b + 0,
               nullptr, nullptr, xj, NJ, 256, 128, 128, 0, nullptr, nullptr};
        P.b = {os, WtI + (size_t)1 * 128 * 256, inter_b + 128,
               nullptr, nullptr, xs, NS, 256, 128, 128, 0, nullptr, nullptr};
        P.blocksA = mbJ;
        k_mgemm<2><<<dim3(gemmB, 1), 256, 0, stream>>>(P);
    }

    // D8: proj GEMM l1 + alpha(l1)
    {
        GPair P;
        P.a = {xj, WtWs + (size_t)3 * 256 * 128, nullptr, nullptr, nullptr,
               hs1, NJ, 128, 256, 256, 0, nullptr, nullptr};
        P.b = {xs, WtWs + (size_t)4 * 256 * 128, nullptr, nullptr, nullptr,
               hs2, NS, 128, 512, 512, 0, nullptr, nullptr};
        P.blocksA = mbJ;
        k_proj_alpha<<<dim3(gemmB + alphaB, 4), 256, 0, stream>>>(
            P, gemmB, xj, xs, wsa, wda, 3, aJ, aS);
    }

    // D9: gather l1
    k_gather_all<<<cdiv(NS + NJ, 4), 256, 0, stream>>>(
        offs, esrc, aJ, aS, hs1, hs2, gat_b + (size_t)3 * 256, oj, os);

    // D10: inter l1
    {
        GPair P;
        P.a = {oj, WtI + (size_t)2 * 128 * 256, inter_b + 2 * 128,
               nullptr, nullptr, xj, NJ, 256, 128, 128, 0, nullptr, nullptr};
        P.b = {os, WtI + (size_t)3 * 128 * 256, inter_b + 3 * 128,
               nullptr, nullptr, xs, NS, 256, 128, 128, 0, nullptr, nullptr};
        P.blocksA = mbJ;
        k_mgemm<2><<<dim3(gemmB, 1), 256, 0, stream>>>(P);
    }

    // D11: final projection + fused scores
    {
        GPair P;
        P.a = {xj, WtJf, bjf, nullptr, nullptr, job_emb, NJ, 128, 128, 128, 0, qv, scores};
        P.b = P.a;
        P.blocksA = mbJ;
        k_mgemm<1><<<dim3(mbJ, 1), 256, 0, stream>>>(P);
    }
}

// Round 9
// 365.358 us; speedup vs baseline: 1.1432x; 1.1432x over previous
//
#include <hip/hip_runtime.h>
#include <hip/hip_bf16.h>
#include <math.h>

#define NJ 30000
#define NS 12000
#define E_JS 300000
#define E_SJ 300000
#define E_SS 150000
#define ETOT (E_JS + E_SJ + E_SS + NS)   // 762000 incl. ss self loops
#define NBINS (NS + NJ + NS)             // 54000 combined dst bins
#define NBUK ((NBINS + 63) / 64)         // 844 coarse buckets (64 bins each)
#define SBERT 384
#define HIST_NB 512                      // 256-thr hist blocks
#define SCAT_NB 120                      // 256-thr scatter blocks
#define CAST_MATS 10
#define CAST_BPM 48                      // max tiles/matrix (W0: 12x4)

static inline int cdiv(int a, int b) { return (a + b - 1) / b; }

typedef __attribute__((ext_vector_type(8))) short bf8_t;
typedef __attribute__((ext_vector_type(4))) float f4_t;
typedef unsigned short u16;

__device__ inline float bf2f(unsigned short u) {
    union { unsigned int i; float f; } z; z.i = ((unsigned int)u) << 16; return z.f;
}
__device__ inline unsigned short f2bf(float f) {
    unsigned int x = __float_as_uint(f);
    unsigned int r = (x + 0x7fffu + ((x >> 16) & 1u)) >> 16;   // RNE
    return (unsigned short)r;
}

// ---------------------------------------------------------------------------
// edge decode for combined CSR
// bin layout: [0,NS) js | [NS,NS+NJ) sj | [NS+NJ,NBINS) ss (incl self loops)
// ---------------------------------------------------------------------------
__device__ inline void edge_decode(int e, const int* js_src, const int* js_dst,
                                   const int* sj_src, const int* sj_dst,
                                   const int* ss_src, const int* ss_dst,
                                   int& src, int& bin) {
    if (e < E_JS) { src = js_src[e]; bin = js_dst[e]; }
    else if (e < E_JS + E_SJ) { int i = e - E_JS; src = sj_src[i]; bin = NS + sj_dst[i]; }
    else if (e < E_JS + E_SJ + E_SS) { int i = e - E_JS - E_SJ; src = ss_src[i]; bin = NS + NJ + ss_dst[i]; }
    else { int i = e - E_JS - E_SJ - E_SS; src = i; bin = NS + NJ + i; }
}

// ---------------------------------------------------------------------------
// k_prep: (a) 10 weight transpose+casts (LDS-tiled, coalesced), (b) wa
// precompute + bcnt zero, (c) qv = query @ Wq + bq.
// blocks: [0,480) castT  [480,492) wa  [492] qvec
// ---------------------------------------------------------------------------
struct CastT { const float* src; unsigned short* dst; int K; int N; };
struct PrepArgs {
    CastT m[CAST_MATS];
    const float* Ws; const float* as_; const float* Wd; const float* ad_;
    float* wsa; float* wda; int* bcnt;
    const float* query; const float* Wq; const float* bq; float* qv;
};

__global__ __launch_bounds__(256) void k_prep(PrepArgs A) {
    __shared__ float ldt[32][33];
    int b = blockIdx.x;
    if (b < CAST_MATS * CAST_BPM) {
        int mi = b / CAST_BPM, bx = b % CAST_BPM;
        CastT cm = A.m[mi];
        int tilesN = cm.N >> 5;
        int total = (cm.K >> 5) * tilesN;
        if (bx >= total) return;
        int tk = bx / tilesN, tn = bx % tilesN;
        int k0 = tk * 32, n0 = tn * 32;
        int col = threadIdx.x & 31;
        int row0 = threadIdx.x >> 5;   // 8 rows per pass
#pragma unroll
        for (int r = 0; r < 4; ++r) {
            int kk = row0 + r * 8;
            ldt[kk][col] = cm.src[(size_t)(k0 + kk) * cm.N + n0 + col];
        }
        __syncthreads();
#pragma unroll
        for (int r = 0; r < 4; ++r) {
            int nn = row0 + r * 8;
            cm.dst[(size_t)(n0 + nn) * cm.K + k0 + col] = f2bf(ldt[col][nn]);
        }
    } else if (b < CAST_MATS * CAST_BPM + 12) {
        int id = (b - CAST_MATS * CAST_BPM) * 256 + threadIdx.x;
        if (id < NBUK) A.bcnt[id] = 0;
        if (id >= 2 * 1536) return;
        int which = id / 1536;
        int r = id % 1536;
        int lr = r / 256;
        int kh = r % 256;
        int k = kh / 2, h = kh % 2;
        const float* W = which ? A.Wd : A.Ws;
        const float* a = which ? A.ad_ : A.as_;
        const float* wrow = W + ((size_t)(lr * 128 + k)) * 256 + h * 128;
        const float* arow = a + (size_t)(lr * 2 + h) * 128;
        float acc = 0.f;
        for (int c2 = 0; c2 < 128; ++c2) acc += wrow[c2] * arow[c2];
        (which ? A.wda : A.wsa)[lr * 256 + k * 2 + h] = acc;
    } else {
        int c = threadIdx.x;
        if (c < 128) {
            float acc = A.bq[c];
            for (int k = 0; k < SBERT; ++k) acc += A.query[k] * A.Wq[(size_t)k * 128 + c];
            A.qv[c] = acc;
        }
    }
}

// ---------------------------------------------------------------------------
// MFMA GEMM body (device fn). BM=64, 4 waves x (16m x 128n).
//   EPI: 0 none->bf16, 1 +bias->fp32 +fused scores, 2 +bias,relu->bf16,
//        3 +bias,LN,relu->bf16.  srcf32: fp32 A converted during staging.
// ---------------------------------------------------------------------------
struct GJob {
    const void* X; const unsigned short* Wt;
    const float* bias; const float* gamma; const float* beta;
    void* Y; int M; int K; int N; int ldY; int srcf32;
    const float* qv; float* sc;
};
struct GPair { GJob a; GJob b; int blocksA; };

template <int EPI>
__device__ void mgemm_body(const GPair& P, int bx, int by) {
    int mb = bx;
    GJob g = (mb < P.blocksA) ? P.a : P.b;
    if (mb >= P.blocksA) mb -= P.blocksA;
    const int n0 = by * 128;
    if (n0 >= g.N) return;
    const int row0 = mb * 64;

    __shared__ __align__(16) unsigned short Al[64][40];
    __shared__ __align__(16) unsigned short Bl[128][40];
    const int t = threadIdx.x;
    const int wave = t >> 6, lane = t & 63;
    const int q = lane >> 4, c = lane & 15;
    const int K = g.K;

    f4_t acc[8];
#pragma unroll
    for (int nt = 0; nt < 8; ++nt) acc[nt] = (f4_t){0.f, 0.f, 0.f, 0.f};

    for (int k0 = 0; k0 < K; k0 += 32) {
#pragma unroll
        for (int it = 0; it < 3; ++it) {
            int idx = t + it * 256;
            int r = idx >> 2, cc = (idx & 3) * 8;
            if (r < 64) {
                int gr = row0 + r;
                if (g.srcf32) {
                    ushort4 lo = make_ushort4(0, 0, 0, 0), hi = lo;
                    if (gr < g.M) {
                        const float* Xf = (const float*)g.X;
                        const float* p = &Xf[(size_t)gr * K + k0 + cc];
                        float4 f0 = *(const float4*)p;
                        float4 f1 = *(const float4*)(p + 4);
                        lo = make_ushort4(f2bf(f0.x), f2bf(f0.y), f2bf(f0.z), f2bf(f0.w));
                        hi = make_ushort4(f2bf(f1.x), f2bf(f1.y), f2bf(f1.z), f2bf(f1.w));
                    }
                    *(ushort4*)&Al[r][cc] = lo;
                    *(ushort4*)&Al[r][cc + 4] = hi;
                } else {
                    const unsigned short* Xb = (const unsigned short*)g.X;
                    uint4 va = (gr < g.M) ? *(const uint4*)&Xb[(size_t)gr * K + k0 + cc]
                                          : make_uint4(0u, 0u, 0u, 0u);
                    *(uint4*)&Al[r][cc] = va;
                }
            } else {
                int br = r - 64;
                *(uint4*)&Bl[br][cc] = *(const uint4*)&g.Wt[(size_t)(n0 + br) * K + k0 + cc];
            }
        }
        __syncthreads();
        bf8_t af = *(const bf8_t*)&Al[wave * 16 + c][q * 8];
#pragma unroll
        for (int nt = 0; nt < 8; ++nt) {
            bf8_t bfr = *(const bf8_t*)&Bl[nt * 16 + c][q * 8];
            acc[nt] = __builtin_amdgcn_mfma_f32_16x16x32_bf16(af, bfr, acc[nt], 0, 0, 0);
        }
        __syncthreads();
    }

    float bcol[8], gcol[8], becol[8], qcol[8];
#pragma unroll
    for (int nt = 0; nt < 8; ++nt) {
        bcol[nt] = (EPI >= 1) ? g.bias[n0 + nt * 16 + c] : 0.f;
        if constexpr (EPI == 3) {
            gcol[nt] = g.gamma[nt * 16 + c];
            becol[nt] = g.beta[nt * 16 + c];
        }
        if constexpr (EPI == 1) qcol[nt] = g.qv[n0 + nt * 16 + c];
    }

#pragma unroll
    for (int r = 0; r < 4; ++r) {
        int grow = row0 + wave * 16 + q * 4 + r;
        float v[8];
#pragma unroll
        for (int nt = 0; nt < 8; ++nt) v[nt] = acc[nt][r] + bcol[nt];
        if constexpr (EPI == 3) {
            float s = 0.f, ss = 0.f;
#pragma unroll
            for (int nt = 0; nt < 8; ++nt) { s += v[nt]; ss += v[nt] * v[nt]; }
#pragma unroll
            for (int m = 8; m >= 1; m >>= 1) {
                s += __shfl_xor(s, m, 64);
                ss += __shfl_xor(ss, m, 64);
            }
            float mu = s * (1.f / 128.f);
            float var = ss * (1.f / 128.f) - mu * mu;
            float rs = rsqrtf(var + 1e-5f);
#pragma unroll
            for (int nt = 0; nt < 8; ++nt)
                v[nt] = fmaxf((v[nt] - mu) * rs * gcol[nt] + becol[nt], 0.f);
        } else if constexpr (EPI == 2) {
#pragma unroll
            for (int nt = 0; nt < 8; ++nt) v[nt] = fmaxf(v[nt], 0.f);
        }
        if constexpr (EPI == 1) {
            float part = 0.f;
#pragma unroll
            for (int nt = 0; nt < 8; ++nt) part += v[nt] * qcol[nt];
#pragma unroll
            for (int m = 8; m >= 1; m >>= 1) part += __shfl_xor(part, m, 64);
            if (c == 0 && grow < g.M) g.sc[grow] = part;
        }
        if (grow < g.M) {
            if constexpr (EPI == 1) {
                float* Y = (float*)g.Y;
#pragma unroll
                for (int nt = 0; nt < 8; ++nt)
                    Y[(size_t)grow * g.ldY + n0 + nt * 16 + c] = v[nt];
            } else {
                unsigned short* Y = (unsigned short*)g.Y;
#pragma unroll
                for (int nt = 0; nt < 8; ++nt)
                    Y[(size_t)grow * g.ldY + n0 + nt * 16 + c] = f2bf(v[nt]);
            }
        }
    }
}

template <int EPI>
__global__ __launch_bounds__(256) void k_mgemm(GPair P) {
    mgemm_body<EPI>(P, blockIdx.x, blockIdx.y);
}

// ---------------------------------------------------------------------------
// alpha body (device fn)
//   aJ[n][4] = {as_js(h0,h1), ad_sj(h0,h1)}
//   aS[n][8] = {as_ss(h0,h1), ad_js(h0,h1), as_sj(h0,h1), ad_ss(h0,h1)}
// ---------------------------------------------------------------------------
__device__ void alpha_body(const unsigned short* xj, const unsigned short* xs,
                           const float* wsa, const float* wda, int l3,
                           float* aJ, float* aS, int b) {
    int wave = threadIdx.x >> 6, lane = threadIdx.x & 63;
    int node = b * 4 + wave;
    if (node < NJ) {
        ushort2 xv = *(const ushort2*)&xj[(size_t)node * 128 + lane * 2];
        float x0 = bf2f(xv.x), x1 = bf2f(xv.y);
        float4 w0 = *(const float4*)&wsa[(size_t)(l3 + 0) * 256 + lane * 4];
        float4 w1 = *(const float4*)&wda[(size_t)(l3 + 1) * 256 + lane * 4];
        float p0 = x0 * w0.x + x1 * w0.z, p1 = x0 * w0.y + x1 * w0.w;
        float p2 = x0 * w1.x + x1 * w1.z, p3 = x0 * w1.y + x1 * w1.w;
#pragma unroll
        for (int m = 32; m >= 1; m >>= 1) {
            p0 += __shfl_xor(p0, m, 64); p1 += __shfl_xor(p1, m, 64);
            p2 += __shfl_xor(p2, m, 64); p3 += __shfl_xor(p3, m, 64);
        }
        if (lane == 0) *(float4*)&aJ[(size_t)node * 4] = make_float4(p0, p1, p2, p3);
    } else if (node < NJ + NS) {
        int n = node - NJ;
        ushort2 xv = *(const ushort2*)&xs[(size_t)n * 128 + lane * 2];
        float x0 = bf2f(xv.x), x1 = bf2f(xv.y);
        float4 wA = *(const float4*)&wsa[(size_t)(l3 + 2) * 256 + lane * 4];
        float4 wB = *(const float4*)&wda[(size_t)(l3 + 0) * 256 + lane * 4];
        float4 wC = *(const float4*)&wsa[(size_t)(l3 + 1) * 256 + lane * 4];
        float4 wD = *(const float4*)&wda[(size_t)(l3 + 2) * 256 + lane * 4];
        float p0 = x0 * wA.x + x1 * wA.z, p1 = x0 * wA.y + x1 * wA.w;
        float p2 = x0 * wB.x + x1 * wB.z, p3 = x0 * wB.y + x1 * wB.w;
        float p4 = x0 * wC.x + x1 * wC.z, p5 = x0 * wC.y + x1 * wC.w;
        float p6 = x0 * wD.x + x1 * wD.z, p7 = x0 * wD.y + x1 * wD.w;
#pragma unroll
        for (int m = 32; m >= 1; m >>= 1) {
            p0 += __shfl_xor(p0, m, 64); p1 += __shfl_xor(p1, m, 64);
            p2 += __shfl_xor(p2, m, 64); p3 += __shfl_xor(p3, m, 64);
            p4 += __shfl_xor(p4, m, 64); p5 += __shfl_xor(p5, m, 64);
            p6 += __shfl_xor(p6, m, 64); p7 += __shfl_xor(p7, m, 64);
        }
        if (lane == 0) {
            float4* o = (float4*)&aS[(size_t)n * 8];
            o[0] = make_float4(p0, p1, p2, p3);
            o[1] = make_float4(p4, p5, p6, p7);
        }
    }
}

// ---------------------------------------------------------------------------
// D2: lin0 GEMM + bucket hist (merged)
// ---------------------------------------------------------------------------
__global__ __launch_bounds__(256) void k_lin0_hist(
    GPair P, int gemmBlocks,
    const int* __restrict__ js_src, const int* __restrict__ js_dst,
    const int* __restrict__ sj_src, const int* __restrict__ sj_dst,
    const int* __restrict__ ss_src, const int* __restrict__ ss_dst,
    int* __restrict__ bcnt) {
    if (blockIdx.x < (unsigned)gemmBlocks) {
        mgemm_body<3>(P, blockIdx.x, blockIdx.y);
        return;
    }
    __shared__ int lh[NBUK];
    int t = threadIdx.x;
    for (int i = t; i < NBUK; i += 256) lh[i] = 0;
    __syncthreads();
    int hb = blockIdx.x - gemmBlocks;
    for (int e = hb * 256 + t; e < ETOT; e += HIST_NB * 256) {
        int src, bin;
        edge_decode(e, js_src, js_dst, sj_src, sj_dst, ss_src, ss_dst, src, bin);
        atomicAdd(&lh[bin >> 6], 1);
    }
    __syncthreads();
    for (int i = t; i < NBUK; i += 256) {
        int v = lh[i];
        if (v) atomicAdd(&bcnt[i], v);
    }
}

// ---------------------------------------------------------------------------
// D3: alpha(l0) + bucket scan (merged)
// ---------------------------------------------------------------------------
__global__ __launch_bounds__(256) void k_alpha_scan(
    const unsigned short* __restrict__ xj, const unsigned short* __restrict__ xs,
    const float* __restrict__ wsa, const float* __restrict__ wda, int l3,
    float* __restrict__ aJ, float* __restrict__ aS, int alphaBlocks,
    const int* __restrict__ bcnt, int* __restrict__ bukoff, int* __restrict__ bukcur) {
    if (blockIdx.x < (unsigned)alphaBlocks) {
        alpha_body(xj, xs, wsa, wda, l3, aJ, aS, blockIdx.x);
        return;
    }
    __shared__ int sd[256];
    int t = threadIdx.x;
    int i0 = t * 4;
    int v0 = (i0 < NBUK) ? bcnt[i0] : 0;
    int v1 = (i0 + 1 < NBUK) ? bcnt[i0 + 1] : 0;
    int v2 = (i0 + 2 < NBUK) ? bcnt[i0 + 2] : 0;
    int v3 = (i0 + 3 < NBUK) ? bcnt[i0 + 3] : 0;
    int csum = v0 + v1 + v2 + v3;
    sd[t] = csum;
    __syncthreads();
    for (int off = 1; off < 256; off <<= 1) {
        int tmp = (t >= off) ? sd[t - off] : 0;
        __syncthreads();
        sd[t] += tmp;
        __syncthreads();
    }
    int excl = sd[t] - csum;
    int p0 = excl, p1 = excl + v0, p2 = excl + v0 + v1, p3 = excl + v0 + v1 + v2;
    if (i0 < NBUK) { bukoff[i0] = p0; bukcur[i0] = p0; }
    if (i0 + 1 < NBUK) { bukoff[i0 + 1] = p1; bukcur[i0 + 1] = p1; }
    if (i0 + 2 < NBUK) { bukoff[i0 + 2] = p2; bukcur[i0 + 2] = p2; }
    if (i0 + 3 < NBUK) { bukoff[i0 + 3] = p3; bukcur[i0 + 3] = p3; }
    if (t == 0) bukoff[NBUK] = ETOT;
}

// ---------------------------------------------------------------------------
// D4: scatter pairs + proj GEMM l0 (merged)
// ---------------------------------------------------------------------------
__global__ __launch_bounds__(256) void k_scatter_proj(
    GPair P, int gemmBlocks,
    const int* __restrict__ js_src, const int* __restrict__ js_dst,
    const int* __restrict__ sj_src, const int* __restrict__ sj_dst,
    const int* __restrict__ ss_src, const int* __restrict__ ss_dst,
    int* __restrict__ bukcur, uint2* __restrict__ pairs) {
    if (blockIdx.x < (unsigned)gemmBlocks) {
        mgemm_body<0>(P, blockIdx.x, blockIdx.y);
        return;
    }
    if (blockIdx.y != 0) return;
    __shared__ int lh[NBUK];
    __shared__ int lbase[NBUK];
    int t = threadIdx.x;
    int sb = blockIdx.x - gemmBlocks;
    const int CH = (ETOT + SCAT_NB - 1) / SCAT_NB;
    const int beg = sb * CH;
    const int endi = (beg + CH < ETOT) ? beg + CH : ETOT;
    for (int i = t; i < NBUK; i += 256) lh[i] = 0;
    __syncthreads();
    for (int e = beg + t; e < endi; e += 256) {
        int src, bin;
        edge_decode(e, js_src, js_dst, sj_src, sj_dst, ss_src, ss_dst, src, bin);
        atomicAdd(&lh[bin >> 6], 1);
    }
    __syncthreads();
    for (int i = t; i < NBUK; i += 256) {
        int v = lh[i];
        lbase[i] = v ? atomicAdd(&bukcur[i], v) : 0;
    }
    __syncthreads();
    for (int i = t; i < NBUK; i += 256) lh[i] = 0;
    __syncthreads();
    for (int e = beg + t; e < endi; e += 256) {
        int src, bin;
        edge_decode(e, js_src, js_dst, sj_src, sj_dst, ss_src, ss_dst, src, bin);
        int bu = bin >> 6;
        int pos = lbase[bu] + atomicAdd(&lh[bu], 1);
        pairs[pos] = make_uint2((unsigned)src, (unsigned)bin);
    }
}

// ---------------------------------------------------------------------------
// D8: proj GEMM l1 (sj only) + alpha(l1) (merged)
// ---------------------------------------------------------------------------
__global__ __launch_bounds__(256) void k_proj_alpha(
    GPair P, int gemmBlocks,
    const unsigned short* __restrict__ xj, const unsigned short* __restrict__ xs,
    const float* __restrict__ wsa, const float* __restrict__ wda, int l3,
    float* __restrict__ aJ, float* __restrict__ aS) {
    if (blockIdx.x < (unsigned)gemmBlocks) {
        mgemm_body<0>(P, blockIdx.x, blockIdx.y);
        return;
    }
    if (blockIdx.y != 0) return;
    alpha_body(xj, xs, wsa, wda, l3, aJ, aS, blockIdx.x - gemmBlocks);
}

// ---------------------------------------------------------------------------
// finalize: one block per bucket, dense contiguous esrc writes
// ---------------------------------------------------------------------------
__global__ __launch_bounds__(256) void k_finalize(
    const uint2* __restrict__ pairs, const int* __restrict__ bukoff,
    int* __restrict__ offs, int* __restrict__ esrc) {
    int b = blockIdx.x, t = threadIdx.x;
    int base = bukoff[b], endi = bukoff[b + 1];
    __shared__ int cnt[64], excl[64], curs[64];
    if (t < 64) cnt[t] = 0;
    __syncthreads();
    for (int i = base + t; i < endi; i += 256)
        atomicAdd(&cnt[pairs[i].y & 63], 1);
    __syncthreads();
    if (t < 64) {
        int v = cnt[t];
        int inc = v;
#pragma unroll
        for (int off = 1; off < 64; off <<= 1) {
            int tmp = __shfl_up(inc, off, 64);
            if (t >= off) inc += tmp;
        }
        excl[t] = inc - v;
        curs[t] = inc - v;
    }
    __syncthreads();
    for (int i = base + t; i < endi; i += 256) {
        uint2 p = pairs[i];
        int lb = p.y & 63;
        int pos = atomicAdd(&curs[lb], 1);
        esrc[base + pos] = (int)p.x;
    }
    if (t < 64) {
        int bin = b * 64 + t;
        if (bin < NBINS) offs[bin] = base + excl[t];
    }
    if (b == 0 && t == 0) offs[NBINS] = ETOT;
}

// ---------------------------------------------------------------------------
// Combined gather, 4-way unrolled edge loop (clamped tail).
// jobOnly=1: only sj relation -> oj (layer 2; skill path is dead code).
// ---------------------------------------------------------------------------
__device__ inline void edge_accum(
    const int* __restrict__ esrc, int beg, int endi,
    const float* __restrict__ aSrc, int sStride, int hOff, float ad,
    const unsigned short* __restrict__ hs, int hsLd, int c,
    float& ax, float& ay, float& az, float& aw, float& den) {
    for (int j = beg; j < endi; j += 4) {
        int j1 = j + 1 < endi ? j + 1 : endi - 1;
        int j2 = j + 2 < endi ? j + 2 : endi - 1;
        int j3 = j + 3 < endi ? j + 3 : endi - 1;
        int s0 = esrc[j], s1 = esrc[j1], s2 = esrc[j2], s3 = esrc[j3];
        float as0 = aSrc[(size_t)s0 * sStride + hOff];
        float as1 = aSrc[(size_t)s1 * sStride + hOff];
        float as2 = aSrc[(size_t)s2 * sStride + hOff];
        float as3 = aSrc[(size_t)s3 * sStride + hOff];
        ushort4 v0 = *(const ushort4*)&hs[(size_t)s0 * hsLd + c];
        ushort4 v1 = *(const ushort4*)&hs[(size_t)s1 * hsLd + c];
        ushort4 v2 = *(const ushort4*)&hs[(size_t)s2 * hsLd + c];
        ushort4 v3 = *(const ushort4*)&hs[(size_t)s3 * hsLd + c];
        float e0 = as0 + ad; e0 = e0 > 0.f ? e0 : 0.2f * e0;
        float e1 = as1 + ad; e1 = e1 > 0.f ? e1 : 0.2f * e1;
        float e2 = as2 + ad; e2 = e2 > 0.f ? e2 : 0.2f * e2;
        float e3 = as3 + ad; e3 = e3 > 0.f ? e3 : 0.2f * e3;
        float p0 = __expf(e0);
        float p1 = (j + 1 < endi) ? __expf(e1) : 0.f;
        float p2 = (j + 2 < endi) ? __expf(e2) : 0.f;
        float p3 = (j + 3 < endi) ? __expf(e3) : 0.f;
        ax += p0 * bf2f(v0.x) + p1 * bf2f(v1.x) + p2 * bf2f(v2.x) + p3 * bf2f(v3.x);
        ay += p0 * bf2f(v0.y) + p1 * bf2f(v1.y) + p2 * bf2f(v2.y) + p3 * bf2f(v3.y);
        az += p0 * bf2f(v0.z) + p1 * bf2f(v1.z) + p2 * bf2f(v2.z) + p3 * bf2f(v3.z);
        aw += p0 * bf2f(v0.w) + p1 * bf2f(v1.w) + p2 * bf2f(v2.w) + p3 * bf2f(v3.w);
        den += p0 + p1 + p2 + p3;
    }
}

__global__ __launch_bounds__(256) void k_gather_all(
    const int* __restrict__ offs, const int* __restrict__ esrc,
    const float* __restrict__ aJ, const float* __restrict__ aS,
    const unsigned short* __restrict__ hs1, const unsigned short* __restrict__ hs2,
    const float* __restrict__ gb,     // gat_b + l3*256
    unsigned short* __restrict__ oj, unsigned short* __restrict__ os,
    int jobOnly) {
    int wave = threadIdx.x >> 6, lane = threadIdx.x & 63;
    int idx = blockIdx.x * 4 + wave;
    int c = lane * 4;
    int h = (c >= 128) ? 1 : 0;
    if (jobOnly) {
        if (idx >= NJ) return;
        int d = idx;
        float ax = 0.f, ay = 0.f, az = 0.f, aw = 0.f, den = 0.f;
        int bb = NS + d;
        edge_accum(esrc, offs[bb], offs[bb + 1], aS, 8, 4 + h, aJ[(size_t)d * 4 + 2 + h],
                   hs2, 512, c, ax, ay, az, aw, den);
        float sc = 1.f / (den + 1e-16f);
        float4 b4 = *(const float4*)&gb[256 + c];
        float o0 = ax * sc + b4.x, o1 = ay * sc + b4.y;
        float o2 = az * sc + b4.z, o3 = aw * sc + b4.w;
        ushort4 o; o.x = f2bf(o0); o.y = f2bf(o1); o.z = f2bf(o2); o.w = f2bf(o3);
        *(ushort4*)&oj[(size_t)d * 256 + c] = o;
        return;
    }
    if (idx < NS) {
        int d = idx;
        float axA = 0.f, ayA = 0.f, azA = 0.f, awA = 0.f, denA = 0.f;
        edge_accum(esrc, offs[d], offs[d + 1], aJ, 4, h, aS[(size_t)d * 8 + 2 + h],
                   hs1, 256, c, axA, ayA, azA, awA, denA);
        float axB = 0.f, ayB = 0.f, azB = 0.f, awB = 0.f, denB = 0.f;
        int bb = NS + NJ + d;
        edge_accum(esrc, offs[bb], offs[bb + 1], aS, 8, h, aS[(size_t)d * 8 + 6 + h],
                   hs2 + 256, 512, c, axB, ayB, azB, awB, denB);
        float scA = 1.f / (denA + 1e-16f);
        float scB = 1.f / (denB + 1e-16f);
        float4 bA = *(const float4*)&gb[c];
        float4 bB = *(const float4*)&gb[512 + c];
        float o0 = axA * scA + bA.x + axB * scB + bB.x;
        float o1 = ayA * scA + bA.y + ayB * scB + bB.y;
        float o2 = azA * scA + bA.z + azB * scB + bB.z;
        float o3 = awA * scA + bA.w + awB * scB + bB.w;
        ushort4 o; o.x = f2bf(o0); o.y = f2bf(o1); o.z = f2bf(o2); o.w = f2bf(o3);
        *(ushort4*)&os[(size_t)d * 256 + c] = o;
    } else if (idx < NS + NJ) {
        int d = idx - NS;
        float ax = 0.f, ay = 0.f, az = 0.f, aw = 0.f, den = 0.f;
        int bb = NS + d;
        edge_accum(esrc, offs[bb], offs[bb + 1], aS, 8, 4 + h, aJ[(size_t)d * 4 + 2 + h],
                   hs2, 512, c, ax, ay, az, aw, den);
        float sc = 1.f / (den + 1e-16f);
        float4 b4 = *(const float4*)&gb[256 + c];
        float o0 = ax * sc + b4.x, o1 = ay * sc + b4.y;
        float o2 = az * sc + b4.z, o3 = aw * sc + b4.w;
        ushort4 o; o.x = f2bf(o0); o.y = f2bf(o1); o.z = f2bf(o2); o.w = f2bf(o3);
        *(ushort4*)&oj[(size_t)d * 256 + c] = o;
    }
}

// ---------------------------------------------------------------------------
extern "C" void kernel_launch(void* const* d_in, const int* in_sizes, int n_in,
                              void* d_out, int out_size, void* d_ws, size_t ws_size,
                              hipStream_t stream) {
    const float* x_job   = (const float*)d_in[0];
    const float* x_skill = (const float*)d_in[1];
    const int* js_src = (const int*)d_in[2];
    const int* js_dst = (const int*)d_in[3];
    const int* sj_src = (const int*)d_in[4];
    const int* sj_dst = (const int*)d_in[5];
    const int* ss_src = (const int*)d_in[6];
    const int* ss_dst = (const int*)d_in[7];
    const float* query    = (const float*)d_in[8];
    const float* W0_job   = (const float*)d_in[9];
    const float* b0_job   = (const float*)d_in[10];
    const float* g0_job   = (const float*)d_in[11];
    const float* be0_job  = (const float*)d_in[12];
    const float* W0_skill = (const float*)d_in[13];
    const float* b0_skill = (const float*)d_in[14];
    const float* g0_skill = (const float*)d_in[15];
    const float* be0_skill= (const float*)d_in[16];
    const float* gat_Ws = (const float*)d_in[17];
    const float* gat_Wd = (const float*)d_in[18];
    const float* gat_as = (const float*)d_in[19];
    const float* gat_ad = (const float*)d_in[20];
    const float* gat_b  = (const float*)d_in[21];
    const float* inter_W = (const float*)d_in[22];
    const float* inter_b = (const float*)d_in[23];
    const float* Wjf = (const float*)d_in[24];
    const float* bjf = (const float*)d_in[25];
    const float* Wq  = (const float*)d_in[26];
    const float* bq  = (const float*)d_in[27];

    char* w = (char*)d_ws;
    auto alloc = [&](size_t bytes) -> void* {
        void* p = (void*)w;
        w += (bytes + 255) & ~(size_t)255;
        return p;
    };
    u16* xj  = (u16*)alloc((size_t)NJ * 128 * 2);
    u16* xs  = (u16*)alloc((size_t)NS * 128 * 2);
    u16* hs1 = (u16*)alloc((size_t)NJ * 256 * 2);
    u16* hs2 = (u16*)alloc((size_t)NS * 512 * 2);
    u16* oj  = (u16*)alloc((size_t)NJ * 256 * 2);
    u16* os  = (u16*)alloc((size_t)NS * 256 * 2);
    u16* WtW0j = (u16*)alloc((size_t)SBERT * 128 * 2);
    u16* WtW0s = (u16*)alloc((size_t)SBERT * 128 * 2);
    u16* WtWs  = (u16*)alloc((size_t)6 * 128 * 256 * 2);
    u16* WtI   = (u16*)alloc((size_t)4 * 256 * 128 * 2);
    u16* WtJf  = (u16*)alloc((size_t)128 * 128 * 2);
    float* aJ = (float*)alloc((size_t)NJ * 4 * 4);
    float* aS = (float*)alloc((size_t)NS * 8 * 4);
    float* wsa = (float*)alloc(6 * 256 * 4);
    float* wda = (float*)alloc(6 * 256 * 4);
    int* bcnt   = (int*)alloc((size_t)NBUK * 4);
    int* bukoff = (int*)alloc((size_t)(NBUK + 1) * 4);
    int* bukcur = (int*)alloc((size_t)NBUK * 4);
    uint2* pairs = (uint2*)alloc((size_t)ETOT * 8);
    int* offs = (int*)alloc((size_t)(NBINS + 1) * 4);
    int* esrc = (int*)alloc((size_t)ETOT * 4);

    float* out = (float*)d_out;
    float* scores  = out;
    float* job_emb = out + NJ;
    float* qv      = out + NJ + (size_t)NJ * 128;

    const int mbJ = cdiv(NJ, 64);   // 469
    const int mbS = cdiv(NS, 64);   // 188
    const int gemmB = mbJ + mbS;    // 657
    const int alphaB = cdiv(NJ + NS, 4);   // 10500

    // D1: prep (coalesced weight transposes + wa + bcnt zero + qvec)
    {
        PrepArgs A;
        A.m[0] = {W0_job, WtW0j, SBERT, 128};
        A.m[1] = {W0_skill, WtW0s, SBERT, 128};
        // needed GAT source projections: js l0 (0), sj l0 (1), ss l0 (2), sj l1 (4)
        A.m[2] = {gat_Ws + (size_t)0 * 128 * 256, WtWs + (size_t)0 * 256 * 128, 128, 256};
        A.m[3] = {gat_Ws + (size_t)1 * 128 * 256, WtWs + (size_t)1 * 256 * 128, 128, 256};
        A.m[4] = {gat_Ws + (size_t)2 * 128 * 256, WtWs + (size_t)2 * 256 * 128, 128, 256};
        A.m[5] = {gat_Ws + (size_t)4 * 128 * 256, WtWs + (size_t)4 * 256 * 128, 128, 256};
        // needed inter: job l0 (0), skill l0 (1), job l1 (2); skill l1 dead
        A.m[6] = {inter_W + (size_t)0 * 256 * 128, WtI + (size_t)0 * 128 * 256, 256, 128};
        A.m[7] = {inter_W + (size_t)1 * 256 * 128, WtI + (size_t)1 * 128 * 256, 256, 128};
        A.m[8] = {inter_W + (size_t)2 * 256 * 128, WtI + (size_t)2 * 128 * 256, 256, 128};
        A.m[9] = {Wjf, WtJf, 128, 128};
        A.Ws = gat_Ws; A.as_ = gat_as; A.Wd = gat_Wd; A.ad_ = gat_ad;
        A.wsa = wsa; A.wda = wda; A.bcnt = bcnt;
        A.query = query; A.Wq = Wq; A.bq = bq; A.qv = qv;
        k_prep<<<CAST_MATS * CAST_BPM + 12 + 1, 256, 0, stream>>>(A);
    }

    // D2: lin0 (LN epilogue, fp32 src) + bucket hist
    {
        GPair P;
        P.a = {x_job, WtW0j, b0_job, g0_job, be0_job, xj, NJ, SBERT, 128, 128, 1, nullptr, nullptr};
        P.b = {x_skill, WtW0s, b0_skill, g0_skill, be0_skill, xs, NS, SBERT, 128, 128, 1, nullptr, nullptr};
        P.blocksA = mbJ;
        k_lin0_hist<<<dim3(gemmB + HIST_NB, 1), 256, 0, stream>>>(
            P, gemmB, js_src, js_dst, sj_src, sj_dst, ss_src, ss_dst, bcnt);
    }

    // D3: alpha(l0) + bucket scan
    k_alpha_scan<<<alphaB + 1, 256, 0, stream>>>(xj, xs, wsa, wda, 0, aJ, aS,
                                                 alphaB, bcnt, bukoff, bukcur);

    // D4: scatter pairs + proj GEMM l0
    {
        GPair P;
        P.a = {xj, WtWs + (size_t)0 * 256 * 128, nullptr, nullptr, nullptr,
               hs1, NJ, 128, 256, 256, 0, nullptr, nullptr};
        P.b = {xs, WtWs + (size_t)1 * 256 * 128, nullptr, nullptr, nullptr,
               hs2, NS, 128, 512, 512, 0, nullptr, nullptr};
        P.blocksA = mbJ;
        k_scatter_proj<<<dim3(gemmB + SCAT_NB, 4), 256, 0, stream>>>(
            P, gemmB, js_src, js_dst, sj_src, sj_dst, ss_src, ss_dst, bukcur, pairs);
    }

    // D5: finalize CSR
    k_finalize<<<NBUK, 256, 0, stream>>>(pairs, bukoff, offs, esrc);

    // D6: gather l0 (full: js+ss -> os, sj -> oj)
    k_gather_all<<<cdiv(NS + NJ, 4), 256, 0, stream>>>(
        offs, esrc, aJ, aS, hs1, hs2, gat_b + 0, oj, os, 0);

    // D7: inter l0 (job + skill)
    {
        GPair P;
        P.a = {oj, WtI + (size_t)0 * 128 * 256, inter_b + 0,
               nullptr, nullptr, xj, NJ, 256, 128, 128, 0, nullptr, nullptr};
        P.b = {os, WtI + (size_t)1 * 128 * 256, inter_b + 128,
               nullptr, nullptr, xs, NS, 256, 128, 128, 0, nullptr, nullptr};
        P.blocksA = mbJ;
        k_mgemm<2><<<dim3(gemmB, 1), 256, 0, stream>>>(P);
    }

    // D8: proj GEMM l1 (sj only: xs @ Ws[sj,l1] -> hs2 cols [0,256)) + alpha(l1)
    {
        GPair P;
        P.a = {xs, WtWs + (size_t)4 * 256 * 128, nullptr, nullptr, nullptr,
               hs2, NS, 128, 256, 512, 0, nullptr, nullptr};
        P.b = P.a;
        P.blocksA = mbS;
        k_proj_alpha<<<dim3(mbS + alphaB, 2), 256, 0, stream>>>(
            P, mbS, xj, xs, wsa, wda, 3, aJ, aS);
    }

    // D9: gather l1 (job dsts only; skill output is dead after layer 2)
    k_gather_all<<<cdiv(NJ, 4), 256, 0, stream>>>(
        offs, esrc, aJ, aS, hs1, hs2, gat_b + (size_t)3 * 256, oj, os, 1);

    // D10: inter l1 (job only; layer-2 xs is dead)
    {
        GPair P;
        P.a = {oj, WtI + (size_t)2 * 128 * 256, inter_b + 2 * 128,
               nullptr, nullptr, xj, NJ, 256, 128, 128, 0, nullptr, nullptr};
        P.b = P.a;
        P.blocksA = mbJ;
        k_mgemm<2><<<dim3(mbJ, 1), 256, 0, stream>>>(P);
    }

    // D11: final projection + fused scores
    {
        GPair P;
        P.a = {xj, WtJf, bjf, nullptr, nullptr, job_emb, NJ, 128, 128, 128, 0, qv, scores};
        P.b = P.a;
        P.blocksA = mbJ;
        k_mgemm<1><<<dim3(mbJ, 1), 256, 0, stream>>>(P);
    }
}

// Round 10
// 344.261 us; speedup vs baseline: 1.2132x; 1.0613x over previous
//
#include <hip/hip_runtime.h>
#include <hip/hip_bf16.h>
#include <math.h>

#define NJ 30000
#define NS 12000
#define E_JS 300000
#define E_SJ 300000
#define E_SS 150000
#define ETOT (E_JS + E_SJ + E_SS + NS)   // 762000 incl. ss self loops
#define NBINS (NS + NJ + NS)             // 54000 combined dst bins
#define NBUK ((NBINS + 63) / 64)         // 844 coarse buckets
#define SBERT 384
#define HIST_NB 512
#define SCAT_NB 120
#define CAST_MATS 10
#define CAST_BPM 48
#define PREP_CAST (CAST_MATS * CAST_BPM)          // 480
#define PREP_WA   (PREP_CAST + 12)                // wa blocks end
#define PREP_QV   PREP_WA                         // qvec block
#define PREP_HIST (PREP_QV + 1)                   // hist blocks start

static inline int cdiv(int a, int b) { return (a + b - 1) / b; }

typedef __attribute__((ext_vector_type(8))) short bf8_t;
typedef __attribute__((ext_vector_type(4))) float f4_t;
typedef unsigned short u16;

__device__ inline float bf2f(unsigned short u) {
    union { unsigned int i; float f; } z; z.i = ((unsigned int)u) << 16; return z.f;
}
__device__ inline unsigned short f2bf(float f) {
    unsigned int x = __float_as_uint(f);
    unsigned int r = (x + 0x7fffu + ((x >> 16) & 1u)) >> 16;   // RNE
    return (unsigned short)r;
}

// ---------------------------------------------------------------------------
// edge decode; bin layout: [0,NS) js | [NS,NS+NJ) sj | [NS+NJ,NBINS) ss+loops
// ---------------------------------------------------------------------------
__device__ inline void edge_decode(int e, const int* js_src, const int* js_dst,
                                   const int* sj_src, const int* sj_dst,
                                   const int* ss_src, const int* ss_dst,
                                   int& src, int& bin) {
    if (e < E_JS) { src = js_src[e]; bin = js_dst[e]; }
    else if (e < E_JS + E_SJ) { int i = e - E_JS; src = sj_src[i]; bin = NS + sj_dst[i]; }
    else if (e < E_JS + E_SJ + E_SS) { int i = e - E_JS - E_SJ; src = ss_src[i]; bin = NS + NJ + ss_dst[i]; }
    else { int i = e - E_JS - E_SJ - E_SS; src = i; bin = NS + NJ + i; }
}

// ---------------------------------------------------------------------------
// D1 k_prep: castT [0,480) | wa [480,492) | qvec [492] | hist [493,493+512)
// bcnt zeroed by hipMemsetAsync before this dispatch.
// ---------------------------------------------------------------------------
struct CastT { const float* src; unsigned short* dst; int K; int N; };
struct PrepArgs {
    CastT m[CAST_MATS];
    const float* Ws; const float* as_; const float* Wd; const float* ad_;
    float* wsa; float* wda; int* bcnt;
    const float* query; const float* Wq; const float* bq; float* qv;
    const int* js_src; const int* js_dst;
    const int* sj_src; const int* sj_dst;
    const int* ss_src; const int* ss_dst;
};

__global__ __launch_bounds__(256) void k_prep(PrepArgs A) {
    __shared__ float ldt[32][33];
    __shared__ int lh[NBUK];
    int b = blockIdx.x;
    if (b < PREP_CAST) {
        int mi = b / CAST_BPM, bx = b % CAST_BPM;
        CastT cm = A.m[mi];
        int tilesN = cm.N >> 5;
        int total = (cm.K >> 5) * tilesN;
        if (bx >= total) return;
        int tk = bx / tilesN, tn = bx % tilesN;
        int k0 = tk * 32, n0 = tn * 32;
        int col = threadIdx.x & 31;
        int row0 = threadIdx.x >> 5;
#pragma unroll
        for (int r = 0; r < 4; ++r) {
            int kk = row0 + r * 8;
            ldt[kk][col] = cm.src[(size_t)(k0 + kk) * cm.N + n0 + col];
        }
        __syncthreads();
#pragma unroll
        for (int r = 0; r < 4; ++r) {
            int nn = row0 + r * 8;
            cm.dst[(size_t)(n0 + nn) * cm.K + k0 + col] = f2bf(ldt[col][nn]);
        }
    } else if (b < PREP_WA) {
        int id = (b - PREP_CAST) * 256 + threadIdx.x;
        if (id >= 2 * 1536) return;
        int which = id / 1536;
        int r = id % 1536;
        int lr = r / 256;
        int kh = r % 256;
        int k = kh / 2, h = kh % 2;
        const float* W = which ? A.Wd : A.Ws;
        const float* a = which ? A.ad_ : A.as_;
        const float* wrow = W + ((size_t)(lr * 128 + k)) * 256 + h * 128;
        const float* arow = a + (size_t)(lr * 2 + h) * 128;
        float acc = 0.f;
        for (int c2 = 0; c2 < 128; ++c2) acc += wrow[c2] * arow[c2];
        (which ? A.wda : A.wsa)[lr * 256 + k * 2 + h] = acc;
    } else if (b == PREP_QV) {
        int c = threadIdx.x;
        if (c < 128) {
            float acc = A.bq[c];
            for (int k = 0; k < SBERT; ++k) acc += A.query[k] * A.Wq[(size_t)k * 128 + c];
            A.qv[c] = acc;
        }
    } else {
        int t = threadIdx.x;
        for (int i = t; i < NBUK; i += 256) lh[i] = 0;
        __syncthreads();
        int hb = b - PREP_HIST;
        for (int e = hb * 256 + t; e < ETOT; e += HIST_NB * 256) {
            int src, bin;
            edge_decode(e, A.js_src, A.js_dst, A.sj_src, A.sj_dst, A.ss_src, A.ss_dst, src, bin);
            atomicAdd(&lh[bin >> 6], 1);
        }
        __syncthreads();
        for (int i = t; i < NBUK; i += 256) {
            int v = lh[i];
            if (v) atomicAdd(&A.bcnt[i], v);
        }
    }
}

// ---------------------------------------------------------------------------
// MFMA GEMM body. BM=64, 4 waves x (16m x 128n).
// EPI: 0 none->bf16, 1 +bias->fp32+scores, 2 +bias,relu->bf16, 3 +bias,LN,relu->bf16
// Optional alpha epilogue (aMode pairs; requires N==128, n0==0).
// ---------------------------------------------------------------------------
struct GJob {
    const void* X; const unsigned short* Wt;
    const float* bias; const float* gamma; const float* beta;
    void* Y; int M; int K; int N; int ldY; int srcf32;
    const float* qv; float* sc;
    int aMode = 0;
    const float* wav0 = nullptr; const float* wav1 = nullptr;
    const float* wav2 = nullptr; const float* wav3 = nullptr;
    float* aOut = nullptr; int aStride = 0;
};
struct GPair { GJob a; GJob b; int blocksA; };

template <int EPI>
__device__ void mgemm_body(const GPair& P, int bx, int by) {
    int mb = bx;
    GJob g = (mb < P.blocksA) ? P.a : P.b;
    if (mb >= P.blocksA) mb -= P.blocksA;
    const int n0 = by * 128;
    if (n0 >= g.N) return;
    const int row0 = mb * 64;

    __shared__ __align__(16) unsigned short Al[64][40];
    __shared__ __align__(16) unsigned short Bl[128][40];
    const int t = threadIdx.x;
    const int wave = t >> 6, lane = t & 63;
    const int q = lane >> 4, c = lane & 15;
    const int K = g.K;

    f4_t acc[8];
#pragma unroll
    for (int nt = 0; nt < 8; ++nt) acc[nt] = (f4_t){0.f, 0.f, 0.f, 0.f};

    for (int k0 = 0; k0 < K; k0 += 32) {
#pragma unroll
        for (int it = 0; it < 3; ++it) {
            int idx = t + it * 256;
            int r = idx >> 2, cc = (idx & 3) * 8;
            if (r < 64) {
                int gr = row0 + r;
                if (g.srcf32) {
                    ushort4 lo = make_ushort4(0, 0, 0, 0), hi = lo;
                    if (gr < g.M) {
                        const float* Xf = (const float*)g.X;
                        const float* p = &Xf[(size_t)gr * K + k0 + cc];
                        float4 f0 = *(const float4*)p;
                        float4 f1 = *(const float4*)(p + 4);
                        lo = make_ushort4(f2bf(f0.x), f2bf(f0.y), f2bf(f0.z), f2bf(f0.w));
                        hi = make_ushort4(f2bf(f1.x), f2bf(f1.y), f2bf(f1.z), f2bf(f1.w));
                    }
                    *(ushort4*)&Al[r][cc] = lo;
                    *(ushort4*)&Al[r][cc + 4] = hi;
                } else {
                    const unsigned short* Xb = (const unsigned short*)g.X;
                    uint4 va = (gr < g.M) ? *(const uint4*)&Xb[(size_t)gr * K + k0 + cc]
                                          : make_uint4(0u, 0u, 0u, 0u);
                    *(uint4*)&Al[r][cc] = va;
                }
            } else {
                int br = r - 64;
                *(uint4*)&Bl[br][cc] = *(const uint4*)&g.Wt[(size_t)(n0 + br) * K + k0 + cc];
            }
        }
        __syncthreads();
        bf8_t af = *(const bf8_t*)&Al[wave * 16 + c][q * 8];
#pragma unroll
        for (int nt = 0; nt < 8; ++nt) {
            bf8_t bfr = *(const bf8_t*)&Bl[nt * 16 + c][q * 8];
            acc[nt] = __builtin_amdgcn_mfma_f32_16x16x32_bf16(af, bfr, acc[nt], 0, 0, 0);
        }
        __syncthreads();
    }

    float bcol[8], gcol[8], becol[8], qcol[8];
#pragma unroll
    for (int nt = 0; nt < 8; ++nt) {
        bcol[nt] = (EPI >= 1) ? g.bias[n0 + nt * 16 + c] : 0.f;
        if constexpr (EPI == 3) {
            gcol[nt] = g.gamma[nt * 16 + c];
            becol[nt] = g.beta[nt * 16 + c];
        }
        if constexpr (EPI == 1) qcol[nt] = g.qv[n0 + nt * 16 + c];
    }

#pragma unroll
    for (int r = 0; r < 4; ++r) {
        int grow = row0 + wave * 16 + q * 4 + r;
        float v[8];
#pragma unroll
        for (int nt = 0; nt < 8; ++nt) v[nt] = acc[nt][r] + bcol[nt];
        if constexpr (EPI == 3) {
            float s = 0.f, ss = 0.f;
#pragma unroll
            for (int nt = 0; nt < 8; ++nt) { s += v[nt]; ss += v[nt] * v[nt]; }
#pragma unroll
            for (int m = 8; m >= 1; m >>= 1) {
                s += __shfl_xor(s, m, 64);
                ss += __shfl_xor(ss, m, 64);
            }
            float mu = s * (1.f / 128.f);
            float var = ss * (1.f / 128.f) - mu * mu;
            float rs = rsqrtf(var + 1e-5f);
#pragma unroll
            for (int nt = 0; nt < 8; ++nt)
                v[nt] = fmaxf((v[nt] - mu) * rs * gcol[nt] + becol[nt], 0.f);
        } else if constexpr (EPI == 2) {
#pragma unroll
            for (int nt = 0; nt < 8; ++nt) v[nt] = fmaxf(v[nt], 0.f);
        }
        if constexpr (EPI == 1) {
            float part = 0.f;
#pragma unroll
            for (int nt = 0; nt < 8; ++nt) part += v[nt] * qcol[nt];
#pragma unroll
            for (int m = 8; m >= 1; m >>= 1) part += __shfl_xor(part, m, 64);
            if (c == 0 && grow < g.M) g.sc[grow] = part;
        }
        // fused alpha (dot of output row with fixed vectors), N==128 only
        if (g.aMode > 0) {
            float pa[8];
#pragma unroll
            for (int i = 0; i < 8; ++i) pa[i] = 0.f;
#pragma unroll
            for (int nt = 0; nt < 8; ++nt) {
                int col = nt * 16 + c;
                float2 w0 = *(const float2*)&g.wav0[col * 2];
                pa[0] += v[nt] * w0.x; pa[1] += v[nt] * w0.y;
                if (g.aMode > 1) {
                    float2 w1 = *(const float2*)&g.wav1[col * 2];
                    pa[2] += v[nt] * w1.x; pa[3] += v[nt] * w1.y;
                }
                if (g.aMode > 2) {
                    float2 w2 = *(const float2*)&g.wav2[col * 2];
                    float2 w3 = *(const float2*)&g.wav3[col * 2];
                    pa[4] += v[nt] * w2.x; pa[5] += v[nt] * w2.y;
                    pa[6] += v[nt] * w3.x; pa[7] += v[nt] * w3.y;
                }
            }
#pragma unroll
            for (int m = 8; m >= 1; m >>= 1) {
                pa[0] += __shfl_xor(pa[0], m, 64); pa[1] += __shfl_xor(pa[1], m, 64);
                pa[2] += __shfl_xor(pa[2], m, 64); pa[3] += __shfl_xor(pa[3], m, 64);
                pa[4] += __shfl_xor(pa[4], m, 64); pa[5] += __shfl_xor(pa[5], m, 64);
                pa[6] += __shfl_xor(pa[6], m, 64); pa[7] += __shfl_xor(pa[7], m, 64);
            }
            if (c == 0 && grow < g.M) {
                float* ao = &g.aOut[(size_t)grow * g.aStride];
                ao[0] = pa[0]; ao[1] = pa[1];
                if (g.aMode > 1) { ao[2] = pa[2]; ao[3] = pa[3]; }
                if (g.aMode > 2) { ao[4] = pa[4]; ao[5] = pa[5]; ao[6] = pa[6]; ao[7] = pa[7]; }
            }
        }
        if (grow < g.M) {
            if constexpr (EPI == 1) {
                float* Y = (float*)g.Y;
#pragma unroll
                for (int nt = 0; nt < 8; ++nt)
                    Y[(size_t)grow * g.ldY + n0 + nt * 16 + c] = v[nt];
            } else {
                unsigned short* Y = (unsigned short*)g.Y;
#pragma unroll
                for (int nt = 0; nt < 8; ++nt)
                    Y[(size_t)grow * g.ldY + n0 + nt * 16 + c] = f2bf(v[nt]);
            }
        }
    }
}

template <int EPI>
__global__ __launch_bounds__(256) void k_mgemm(GPair P) {
    mgemm_body<EPI>(P, blockIdx.x, blockIdx.y);
}

// ---------------------------------------------------------------------------
// D2: lin0 (LN+relu, alpha-l0 fused) + bucket scan (last block)
// ---------------------------------------------------------------------------
__global__ __launch_bounds__(256) void k_lin0_scan(
    GPair P, int gemmBlocks,
    const int* __restrict__ bcnt, int* __restrict__ bukoff, int* __restrict__ bukcur) {
    if (blockIdx.x < (unsigned)gemmBlocks) {
        mgemm_body<3>(P, blockIdx.x, 0);
        return;
    }
    __shared__ int sd[256];
    int t = threadIdx.x;
    int i0 = t * 4;
    int v0 = (i0 < NBUK) ? bcnt[i0] : 0;
    int v1 = (i0 + 1 < NBUK) ? bcnt[i0 + 1] : 0;
    int v2 = (i0 + 2 < NBUK) ? bcnt[i0 + 2] : 0;
    int v3 = (i0 + 3 < NBUK) ? bcnt[i0 + 3] : 0;
    int csum = v0 + v1 + v2 + v3;
    sd[t] = csum;
    __syncthreads();
    for (int off = 1; off < 256; off <<= 1) {
        int tmp = (t >= off) ? sd[t - off] : 0;
        __syncthreads();
        sd[t] += tmp;
        __syncthreads();
    }
    int excl = sd[t] - csum;
    int p0 = excl, p1 = excl + v0, p2 = excl + v0 + v1, p3 = excl + v0 + v1 + v2;
    if (i0 < NBUK) { bukoff[i0] = p0; bukcur[i0] = p0; }
    if (i0 + 1 < NBUK) { bukoff[i0 + 1] = p1; bukcur[i0 + 1] = p1; }
    if (i0 + 2 < NBUK) { bukoff[i0 + 2] = p2; bukcur[i0 + 2] = p2; }
    if (i0 + 3 < NBUK) { bukoff[i0 + 3] = p3; bukcur[i0 + 3] = p3; }
    if (t == 0) bukoff[NBUK] = ETOT;
}

// ---------------------------------------------------------------------------
// D3: scatter pairs + proj GEMM l0 (merged)
// ---------------------------------------------------------------------------
__global__ __launch_bounds__(256) void k_scatter_proj(
    GPair P, int gemmBlocks,
    const int* __restrict__ js_src, const int* __restrict__ js_dst,
    const int* __restrict__ sj_src, const int* __restrict__ sj_dst,
    const int* __restrict__ ss_src, const int* __restrict__ ss_dst,
    int* __restrict__ bukcur, uint2* __restrict__ pairs) {
    if (blockIdx.x < (unsigned)gemmBlocks) {
        mgemm_body<0>(P, blockIdx.x, blockIdx.y);
        return;
    }
    if (blockIdx.y != 0) return;
    __shared__ int lh[NBUK];
    __shared__ int lbase[NBUK];
    int t = threadIdx.x;
    int sb = blockIdx.x - gemmBlocks;
    const int CH = (ETOT + SCAT_NB - 1) / SCAT_NB;
    const int beg = sb * CH;
    const int endi = (beg + CH < ETOT) ? beg + CH : ETOT;
    for (int i = t; i < NBUK; i += 256) lh[i] = 0;
    __syncthreads();
    for (int e = beg + t; e < endi; e += 256) {
        int src, bin;
        edge_decode(e, js_src, js_dst, sj_src, sj_dst, ss_src, ss_dst, src, bin);
        atomicAdd(&lh[bin >> 6], 1);
    }
    __syncthreads();
    for (int i = t; i < NBUK; i += 256) {
        int v = lh[i];
        lbase[i] = v ? atomicAdd(&bukcur[i], v) : 0;
    }
    __syncthreads();
    for (int i = t; i < NBUK; i += 256) lh[i] = 0;
    __syncthreads();
    for (int e = beg + t; e < endi; e += 256) {
        int src, bin;
        edge_decode(e, js_src, js_dst, sj_src, sj_dst, ss_src, ss_dst, src, bin);
        int bu = bin >> 6;
        int pos = lbase[bu] + atomicAdd(&lh[bu], 1);
        pairs[pos] = make_uint2((unsigned)src, (unsigned)bin);
    }
}

// ---------------------------------------------------------------------------
// D4: finalize — one block per bucket, dense contiguous esrc writes
// ---------------------------------------------------------------------------
__global__ __launch_bounds__(256) void k_finalize(
    const uint2* __restrict__ pairs, const int* __restrict__ bukoff,
    int* __restrict__ offs, int* __restrict__ esrc) {
    int b = blockIdx.x, t = threadIdx.x;
    int base = bukoff[b], endi = bukoff[b + 1];
    __shared__ int cnt[64], excl[64], curs[64];
    if (t < 64) cnt[t] = 0;
    __syncthreads();
    for (int i = base + t; i < endi; i += 256)
        atomicAdd(&cnt[pairs[i].y & 63], 1);
    __syncthreads();
    if (t < 64) {
        int v = cnt[t];
        int inc = v;
#pragma unroll
        for (int off = 1; off < 64; off <<= 1) {
            int tmp = __shfl_up(inc, off, 64);
            if (t >= off) inc += tmp;
        }
        excl[t] = inc - v;
        curs[t] = inc - v;
    }
    __syncthreads();
    for (int i = base + t; i < endi; i += 256) {
        uint2 p = pairs[i];
        int lb = p.y & 63;
        int pos = atomicAdd(&curs[lb], 1);
        esrc[base + pos] = (int)p.x;
    }
    if (t < 64) {
        int bin = b * 64 + t;
        if (bin < NBINS) offs[bin] = base + excl[t];
    }
    if (b == 0 && t == 0) offs[NBINS] = ETOT;
}

// ---------------------------------------------------------------------------
// Gather, 4-way unrolled edge loop (clamped tail).
// ---------------------------------------------------------------------------
__device__ inline void edge_accum(
    const int* __restrict__ esrc, int beg, int endi,
    const float* __restrict__ aSrc, int sStride, int hOff, float ad,
    const unsigned short* __restrict__ hs, int hsLd, int c,
    float& ax, float& ay, float& az, float& aw, float& den) {
    for (int j = beg; j < endi; j += 4) {
        int j1 = j + 1 < endi ? j + 1 : endi - 1;
        int j2 = j + 2 < endi ? j + 2 : endi - 1;
        int j3 = j + 3 < endi ? j + 3 : endi - 1;
        int s0 = esrc[j], s1 = esrc[j1], s2 = esrc[j2], s3 = esrc[j3];
        float as0 = aSrc[(size_t)s0 * sStride + hOff];
        float as1 = aSrc[(size_t)s1 * sStride + hOff];
        float as2 = aSrc[(size_t)s2 * sStride + hOff];
        float as3 = aSrc[(size_t)s3 * sStride + hOff];
        ushort4 v0 = *(const ushort4*)&hs[(size_t)s0 * hsLd + c];
        ushort4 v1 = *(const ushort4*)&hs[(size_t)s1 * hsLd + c];
        ushort4 v2 = *(const ushort4*)&hs[(size_t)s2 * hsLd + c];
        ushort4 v3 = *(const ushort4*)&hs[(size_t)s3 * hsLd + c];
        float e0 = as0 + ad; e0 = e0 > 0.f ? e0 : 0.2f * e0;
        float e1 = as1 + ad; e1 = e1 > 0.f ? e1 : 0.2f * e1;
        float e2 = as2 + ad; e2 = e2 > 0.f ? e2 : 0.2f * e2;
        float e3 = as3 + ad; e3 = e3 > 0.f ? e3 : 0.2f * e3;
        float p0 = __expf(e0);
        float p1 = (j + 1 < endi) ? __expf(e1) : 0.f;
        float p2 = (j + 2 < endi) ? __expf(e2) : 0.f;
        float p3 = (j + 3 < endi) ? __expf(e3) : 0.f;
        ax += p0 * bf2f(v0.x) + p1 * bf2f(v1.x) + p2 * bf2f(v2.x) + p3 * bf2f(v3.x);
        ay += p0 * bf2f(v0.y) + p1 * bf2f(v1.y) + p2 * bf2f(v2.y) + p3 * bf2f(v3.y);
        az += p0 * bf2f(v0.z) + p1 * bf2f(v1.z) + p2 * bf2f(v2.z) + p3 * bf2f(v3.z);
        aw += p0 * bf2f(v0.w) + p1 * bf2f(v1.w) + p2 * bf2f(v2.w) + p3 * bf2f(v3.w);
        den += p0 + p1 + p2 + p3;
    }
}

__global__ __launch_bounds__(256) void k_gather_all(
    const int* __restrict__ offs, const int* __restrict__ esrc,
    const float* __restrict__ aJ, const float* __restrict__ aS,
    const unsigned short* __restrict__ hs1,          // js src rows, ld 256
    const unsigned short* __restrict__ hsss, int ssLd,   // ss src rows (pre-offset)
    const unsigned short* __restrict__ hsj, int sjLd,    // sj src rows
    const float* __restrict__ gb,
    unsigned short* __restrict__ oj, unsigned short* __restrict__ os,
    int jobOnly) {
    int wave = threadIdx.x >> 6, lane = threadIdx.x & 63;
    int idx = blockIdx.x * 4 + wave;
    int c = lane * 4;
    int h = (c >= 128) ? 1 : 0;
    if (jobOnly) {
        if (idx >= NJ) return;
        int d = idx;
        float ax = 0.f, ay = 0.f, az = 0.f, aw = 0.f, den = 0.f;
        int bb = NS + d;
        edge_accum(esrc, offs[bb], offs[bb + 1], aS, 8, 4 + h, aJ[(size_t)d * 4 + 2 + h],
                   hsj, sjLd, c, ax, ay, az, aw, den);
        float sc = 1.f / (den + 1e-16f);
        float4 b4 = *(const float4*)&gb[256 + c];
        float o0 = ax * sc + b4.x, o1 = ay * sc + b4.y;
        float o2 = az * sc + b4.z, o3 = aw * sc + b4.w;
        ushort4 o; o.x = f2bf(o0); o.y = f2bf(o1); o.z = f2bf(o2); o.w = f2bf(o3);
        *(ushort4*)&oj[(size_t)d * 256 + c] = o;
        return;
    }
    if (idx < NS) {
        int d = idx;
        float axA = 0.f, ayA = 0.f, azA = 0.f, awA = 0.f, denA = 0.f;
        edge_accum(esrc, offs[d], offs[d + 1], aJ, 4, h, aS[(size_t)d * 8 + 2 + h],
                   hs1, 256, c, axA, ayA, azA, awA, denA);
        float axB = 0.f, ayB = 0.f, azB = 0.f, awB = 0.f, denB = 0.f;
        int bb = NS + NJ + d;
        edge_accum(esrc, offs[bb], offs[bb + 1], aS, 8, h, aS[(size_t)d * 8 + 6 + h],
                   hsss, ssLd, c, axB, ayB, azB, awB, denB);
        float scA = 1.f / (denA + 1e-16f);
        float scB = 1.f / (denB + 1e-16f);
        float4 bA = *(const float4*)&gb[c];
        float4 bB = *(const float4*)&gb[512 + c];
        float o0 = axA * scA + bA.x + axB * scB + bB.x;
        float o1 = ayA * scA + bA.y + ayB * scB + bB.y;
        float o2 = azA * scA + bA.z + azB * scB + bB.z;
        float o3 = awA * scA + bA.w + awB * scB + bB.w;
        ushort4 o; o.x = f2bf(o0); o.y = f2bf(o1); o.z = f2bf(o2); o.w = f2bf(o3);
        *(ushort4*)&os[(size_t)d * 256 + c] = o;
    } else if (idx < NS + NJ) {
        int d = idx - NS;
        float ax = 0.f, ay = 0.f, az = 0.f, aw = 0.f, den = 0.f;
        int bb = NS + d;
        edge_accum(esrc, offs[bb], offs[bb + 1], aS, 8, 4 + h, aJ[(size_t)d * 4 + 2 + h],
                   hsj, sjLd, c, ax, ay, az, aw, den);
        float sc = 1.f / (den + 1e-16f);
        float4 b4 = *(const float4*)&gb[256 + c];
        float o0 = ax * sc + b4.x, o1 = ay * sc + b4.y;
        float o2 = az * sc + b4.z, o3 = aw * sc + b4.w;
        ushort4 o; o.x = f2bf(o0); o.y = f2bf(o1); o.z = f2bf(o2); o.w = f2bf(o3);
        *(ushort4*)&oj[(size_t)d * 256 + c] = o;
    }
}

// ---------------------------------------------------------------------------
// Two-stage fused GEMM: Y1 = relu(X @ Wt1 + bias1) kept in regs/LDS (bf16),
// optional single-pair alpha from Y1 rows, optional stage2 Y2 = Y1 @ Wt2 (+b2)
// with K2=128; y2f32 adds fused scores. Stage-1 N = 128.
// ---------------------------------------------------------------------------
struct FJob {
    const unsigned short* X; const unsigned short* Wt1; const float* bias1;
    int M; int K1;
    const float* wa; float* aOut; int aStride;   // single pair (or wa==null)
    const unsigned short* Wt2; const float* bias2; int N2;
    void* Y2; int ldY2; int y2f32;
    const float* qv; float* sc;
};
struct FPair { FJob a; FJob b; int blocksA; };

__global__ __launch_bounds__(256) void k_fused2(FPair P) {
    int mb = blockIdx.x;
    FJob g = (mb < P.blocksA) ? P.a : P.b;
    if (mb >= P.blocksA) mb -= P.blocksA;
    const int row0 = mb * 64;

    __shared__ __align__(16) unsigned short Al[64][40];
    __shared__ __align__(16) unsigned short Bl[128][40];
    __shared__ __align__(16) unsigned short Y1l[4][64][40];
    const int t = threadIdx.x;
    const int wave = t >> 6, lane = t & 63;
    const int q = lane >> 4, c = lane & 15;

    f4_t acc[8];
#pragma unroll
    for (int nt = 0; nt < 8; ++nt) acc[nt] = (f4_t){0.f, 0.f, 0.f, 0.f};

    for (int k0 = 0; k0 < g.K1; k0 += 32) {
#pragma unroll
        for (int it = 0; it < 3; ++it) {
            int idx = t + it * 256;
            int r = idx >> 2, cc = (idx & 3) * 8;
            if (r < 64) {
                int gr = row0 + r;
                uint4 va = (gr < g.M) ? *(const uint4*)&g.X[(size_t)gr * g.K1 + k0 + cc]
                                      : make_uint4(0u, 0u, 0u, 0u);
                *(uint4*)&Al[r][cc] = va;
            } else {
                int br = r - 64;
                *(uint4*)&Bl[br][cc] = *(const uint4*)&g.Wt1[(size_t)br * g.K1 + k0 + cc];
            }
        }
        __syncthreads();
        bf8_t af = *(const bf8_t*)&Al[wave * 16 + c][q * 8];
#pragma unroll
        for (int nt = 0; nt < 8; ++nt) {
            bf8_t bfr = *(const bf8_t*)&Bl[nt * 16 + c][q * 8];
            acc[nt] = __builtin_amdgcn_mfma_f32_16x16x32_bf16(af, bfr, acc[nt], 0, 0, 0);
        }
        __syncthreads();
    }

    // epilogue 1: bias + relu, optional alpha, write Y1 -> LDS (chunked layout)
    float bcol[8];
#pragma unroll
    for (int nt = 0; nt < 8; ++nt) bcol[nt] = g.bias1[nt * 16 + c];
#pragma unroll
    for (int r = 0; r < 4; ++r) {
        int row = wave * 16 + q * 4 + r;
        int grow = row0 + row;
        float v[8];
#pragma unroll
        for (int nt = 0; nt < 8; ++nt) v[nt] = fmaxf(acc[nt][r] + bcol[nt], 0.f);
        if (g.wa) {
            float pa0 = 0.f, pa1 = 0.f;
#pragma unroll
            for (int nt = 0; nt < 8; ++nt) {
                float2 w0 = *(const float2*)&g.wa[(nt * 16 + c) * 2];
                pa0 += v[nt] * w0.x; pa1 += v[nt] * w0.y;
            }
#pragma unroll
            for (int m = 8; m >= 1; m >>= 1) {
                pa0 += __shfl_xor(pa0, m, 64);
                pa1 += __shfl_xor(pa1, m, 64);
            }
            if (c == 0 && grow < g.M) {
                g.aOut[(size_t)grow * g.aStride + 0] = pa0;
                g.aOut[(size_t)grow * g.aStride + 1] = pa1;
            }
        }
#pragma unroll
        for (int nt = 0; nt < 8; ++nt)
            Y1l[nt >> 1][row][(nt & 1) * 16 + c] = f2bf(v[nt]);
    }
    if (g.N2 == 0) return;
    __syncthreads();

    // stage 2: Y2[64 x N2] = Y1 @ Wt2 (K2 = 128)
    for (int n2 = 0; n2 < g.N2; n2 += 128) {
        f4_t acc2[8];
#pragma unroll
        for (int nt = 0; nt < 8; ++nt) acc2[nt] = (f4_t){0.f, 0.f, 0.f, 0.f};
        for (int k0 = 0; k0 < 128; k0 += 32) {
#pragma unroll
            for (int it = 0; it < 2; ++it) {
                int idx = t + it * 256;
                int br = idx >> 2, cc = (idx & 3) * 8;
                *(uint4*)&Bl[br][cc] = *(const uint4*)&g.Wt2[(size_t)(n2 + br) * 128 + k0 + cc];
            }
            __syncthreads();
            bf8_t af = *(const bf8_t*)&Y1l[k0 >> 5][wave * 16 + c][q * 8];
#pragma unroll
            for (int nt = 0; nt < 8; ++nt) {
                bf8_t bfr = *(const bf8_t*)&Bl[nt * 16 + c][q * 8];
                acc2[nt] = __builtin_amdgcn_mfma_f32_16x16x32_bf16(af, bfr, acc2[nt], 0, 0, 0);
            }
            __syncthreads();
        }
        float b2[8], qcol[8];
#pragma unroll
        for (int nt = 0; nt < 8; ++nt) {
            b2[nt] = g.bias2 ? g.bias2[n2 + nt * 16 + c] : 0.f;
            if (g.y2f32) qcol[nt] = g.qv[n2 + nt * 16 + c];
        }
#pragma unroll
        for (int r = 0; r < 4; ++r) {
            int grow = row0 + wave * 16 + q * 4 + r;
            float v[8];
#pragma unroll
            for (int nt = 0; nt < 8; ++nt) v[nt] = acc2[nt][r] + b2[nt];
            if (g.y2f32) {
                float part = 0.f;
#pragma unroll
                for (int nt = 0; nt < 8; ++nt) part += v[nt] * qcol[nt];
#pragma unroll
                for (int m = 8; m >= 1; m >>= 1) part += __shfl_xor(part, m, 64);
                if (c == 0 && grow < g.M) g.sc[grow] = part;
                if (grow < g.M) {
                    float* Y = (float*)g.Y2;
#pragma unroll
                    for (int nt = 0; nt < 8; ++nt)
                        Y[(size_t)grow * g.ldY2 + n2 + nt * 16 + c] = v[nt];
                }
            } else if (grow < g.M) {
                unsigned short* Y = (unsigned short*)g.Y2;
#pragma unroll
                for (int nt = 0; nt < 8; ++nt)
                    Y[(size_t)grow * g.ldY2 + n2 + nt * 16 + c] = f2bf(v[nt]);
            }
        }
    }
}

// ---------------------------------------------------------------------------
extern "C" void kernel_launch(void* const* d_in, const int* in_sizes, int n_in,
                              void* d_out, int out_size, void* d_ws, size_t ws_size,
                              hipStream_t stream) {
    const float* x_job   = (const float*)d_in[0];
    const float* x_skill = (const float*)d_in[1];
    const int* js_src = (const int*)d_in[2];
    const int* js_dst = (const int*)d_in[3];
    const int* sj_src = (const int*)d_in[4];
    const int* sj_dst = (const int*)d_in[5];
    const int* ss_src = (const int*)d_in[6];
    const int* ss_dst = (const int*)d_in[7];
    const float* query    = (const float*)d_in[8];
    const float* W0_job   = (const float*)d_in[9];
    const float* b0_job   = (const float*)d_in[10];
    const float* g0_job   = (const float*)d_in[11];
    const float* be0_job  = (const float*)d_in[12];
    const float* W0_skill = (const float*)d_in[13];
    const float* b0_skill = (const float*)d_in[14];
    const float* g0_skill = (const float*)d_in[15];
    const float* be0_skill= (const float*)d_in[16];
    const float* gat_Ws = (const float*)d_in[17];
    const float* gat_Wd = (const float*)d_in[18];
    const float* gat_as = (const float*)d_in[19];
    const float* gat_ad = (const float*)d_in[20];
    const float* gat_b  = (const float*)d_in[21];
    const float* inter_W = (const float*)d_in[22];
    const float* inter_b = (const float*)d_in[23];
    const float* Wjf = (const float*)d_in[24];
    const float* bjf = (const float*)d_in[25];
    const float* Wq  = (const float*)d_in[26];
    const float* bq  = (const float*)d_in[27];

    char* w = (char*)d_ws;
    auto alloc = [&](size_t bytes) -> void* {
        void* p = (void*)w;
        w += (bytes + 255) & ~(size_t)255;
        return p;
    };
    u16* xj  = (u16*)alloc((size_t)NJ * 128 * 2);
    u16* xs  = (u16*)alloc((size_t)NS * 128 * 2);
    u16* hs1 = (u16*)alloc((size_t)NJ * 256 * 2);
    u16* hs2 = (u16*)alloc((size_t)NS * 512 * 2);
    u16* hs3 = (u16*)alloc((size_t)NS * 256 * 2);
    u16* oj  = (u16*)alloc((size_t)NJ * 256 * 2);
    u16* os  = (u16*)alloc((size_t)NS * 256 * 2);
    u16* WtW0j = (u16*)alloc((size_t)SBERT * 128 * 2);
    u16* WtW0s = (u16*)alloc((size_t)SBERT * 128 * 2);
    u16* WtWs  = (u16*)alloc((size_t)6 * 128 * 256 * 2);
    u16* WtI   = (u16*)alloc((size_t)4 * 256 * 128 * 2);
    u16* WtJf  = (u16*)alloc((size_t)128 * 128 * 2);
    float* aJ = (float*)alloc((size_t)NJ * 4 * 4);
    float* aS = (float*)alloc((size_t)NS * 8 * 4);
    float* wsa = (float*)alloc(6 * 256 * 4);
    float* wda = (float*)alloc(6 * 256 * 4);
    int* bcnt   = (int*)alloc((size_t)NBUK * 4);
    int* bukoff = (int*)alloc((size_t)(NBUK + 1) * 4);
    int* bukcur = (int*)alloc((size_t)NBUK * 4);
    uint2* pairs = (uint2*)alloc((size_t)ETOT * 8);
    int* offs = (int*)alloc((size_t)(NBINS + 1) * 4);
    int* esrc = (int*)alloc((size_t)ETOT * 4);

    float* out = (float*)d_out;
    float* scores  = out;
    float* job_emb = out + NJ;
    float* qv      = out + NJ + (size_t)NJ * 128;

    const int mbJ = cdiv(NJ, 64);   // 469
    const int mbS = cdiv(NS, 64);   // 188
    const int gemmB = mbJ + mbS;    // 657

    // M0: zero bucket counters (graph-capturable memset node)
    hipMemsetAsync(bcnt, 0, (size_t)NBUK * 4, stream);

    // D1: prep (weight transposes + wa + qvec + bucket hist)
    {
        PrepArgs A;
        A.m[0] = {W0_job, WtW0j, SBERT, 128};
        A.m[1] = {W0_skill, WtW0s, SBERT, 128};
        A.m[2] = {gat_Ws + (size_t)0 * 128 * 256, WtWs + (size_t)0 * 256 * 128, 128, 256};
        A.m[3] = {gat_Ws + (size_t)1 * 128 * 256, WtWs + (size_t)1 * 256 * 128, 128, 256};
        A.m[4] = {gat_Ws + (size_t)2 * 128 * 256, WtWs + (size_t)2 * 256 * 128, 128, 256};
        A.m[5] = {gat_Ws + (size_t)4 * 128 * 256, WtWs + (size_t)4 * 256 * 128, 128, 256};
        A.m[6] = {inter_W + (size_t)0 * 256 * 128, WtI + (size_t)0 * 128 * 256, 256, 128};
        A.m[7] = {inter_W + (size_t)1 * 256 * 128, WtI + (size_t)1 * 128 * 256, 256, 128};
        A.m[8] = {inter_W + (size_t)2 * 256 * 128, WtI + (size_t)2 * 128 * 256, 256, 128};
        A.m[9] = {Wjf, WtJf, 128, 128};
        A.Ws = gat_Ws; A.as_ = gat_as; A.Wd = gat_Wd; A.ad_ = gat_ad;
        A.wsa = wsa; A.wda = wda; A.bcnt = bcnt;
        A.query = query; A.Wq = Wq; A.bq = bq; A.qv = qv;
        A.js_src = js_src; A.js_dst = js_dst;
        A.sj_src = sj_src; A.sj_dst = sj_dst;
        A.ss_src = ss_src; A.ss_dst = ss_dst;
        k_prep<<<PREP_HIST + HIST_NB, 256, 0, stream>>>(A);
    }

    // D2: lin0 (LN+relu, fp32 src, alpha-l0 fused) + bucket scan
    {
        GPair P;
        P.a = {x_job, WtW0j, b0_job, g0_job, be0_job, xj, NJ, SBERT, 128, 128, 1,
               nullptr, nullptr, 2, wsa + 0, wda + 256, nullptr, nullptr, aJ, 4};
        P.b = {x_skill, WtW0s, b0_skill, g0_skill, be0_skill, xs, NS, SBERT, 128, 128, 1,
               nullptr, nullptr, 4, wsa + 2 * 256, wda + 0, wsa + 1 * 256, wda + 2 * 256, aS, 8};
        P.blocksA = mbJ;
        k_lin0_scan<<<dim3(gemmB + 1, 1), 256, 0, stream>>>(P, gemmB, bcnt, bukoff, bukcur);
    }

    // D3: scatter pairs + proj GEMM l0
    {
        GPair P;
        P.a = {xj, WtWs + (size_t)0 * 256 * 128, nullptr, nullptr, nullptr,
               hs1, NJ, 128, 256, 256, 0, nullptr, nullptr};
        P.b = {xs, WtWs + (size_t)1 * 256 * 128, nullptr, nullptr, nullptr,
               hs2, NS, 128, 512, 512, 0, nullptr, nullptr};
        P.blocksA = mbJ;
        k_scatter_proj<<<dim3(gemmB + SCAT_NB, 4), 256, 0, stream>>>(
            P, gemmB, js_src, js_dst, sj_src, sj_dst, ss_src, ss_dst, bukcur, pairs);
    }

    // D4: finalize CSR
    k_finalize<<<NBUK, 256, 0, stream>>>(pairs, bukoff, offs, esrc);

    // D5: gather l0 (full)
    k_gather_all<<<cdiv(NS + NJ, 4), 256, 0, stream>>>(
        offs, esrc, aJ, aS, hs1, hs2 + 256, 512, hs2, 512, gat_b, oj, os, 0);

    // D6: fused inter-l0. Job: relu GEMM -> aJ-l1 only (no output).
    //     Skill: relu GEMM -> aS-l1 + stage2 @Ws[sj,l1] -> hs3.
    {
        FPair P;
        P.a = {oj, WtI + (size_t)0 * 128 * 256, inter_b + 0, NJ, 256,
               wda + (size_t)4 * 256, aJ + 2, 4,
               nullptr, nullptr, 0, nullptr, 0, 0, nullptr, nullptr};
        P.b = {os, WtI + (size_t)1 * 128 * 256, inter_b + 128, NS, 256,
               wsa + (size_t)4 * 256, aS + 4, 8,
               WtWs + (size_t)4 * 256 * 128, nullptr, 256, hs3, 256, 0, nullptr, nullptr};
        P.blocksA = mbJ;
        k_fused2<<<dim3(gemmB, 1), 256, 0, stream>>>(P);
    }

    // D7: gather l1 (job dsts only, sj from hs3)
    k_gather_all<<<cdiv(NJ, 4), 256, 0, stream>>>(
        offs, esrc, aJ, aS, nullptr, nullptr, 0, hs3, 256,
        gat_b + (size_t)3 * 256, oj, nullptr, 1);

    // D8: fused inter-l1 + final projection + scores
    {
        FPair P;
        P.a = {oj, WtI + (size_t)2 * 128 * 256, inter_b + 2 * 128, NJ, 256,
               nullptr, nullptr, 0,
               WtJf, bjf, 128, job_emb, 128, 1, qv, scores};
        P.b = P.a;
        P.blocksA = mbJ;
        k_fused2<<<dim3(mbJ, 1), 256, 0, stream>>>(P);
    }
}

// Round 11
// 334.898 us; speedup vs baseline: 1.2471x; 1.0280x over previous
//
#include <hip/hip_runtime.h>
#include <hip/hip_bf16.h>
#include <math.h>

#define NJ 30000
#define NS 12000
#define E_JS 300000
#define E_SJ 300000
#define E_SS 150000
#define ETOT (E_JS + E_SJ + E_SS + NS)   // 762000 incl. ss self loops
#define NBINS (NS + NJ + NS)             // 54000 combined dst bins
#define NBUK ((NBINS + 63) / 64)         // 844 coarse buckets
#define SBERT 384
#define HIST_NB 512
#define SCAT_NB 120
#define CAST_MATS 10
#define CAST_BPM 48
#define PREP_CAST (CAST_MATS * CAST_BPM)          // 480
#define PREP_WA   (PREP_CAST + 12)
#define PREP_QV   PREP_WA
#define PREP_HIST (PREP_QV + 1)

static inline int cdiv(int a, int b) { return (a + b - 1) / b; }

typedef __attribute__((ext_vector_type(8))) short bf8_t;
typedef __attribute__((ext_vector_type(4))) float f4_t;
typedef unsigned short u16;

__device__ inline float bf2f(unsigned short u) {
    union { unsigned int i; float f; } z; z.i = ((unsigned int)u) << 16; return z.f;
}
__device__ inline unsigned short f2bf(float f) {
    unsigned int x = __float_as_uint(f);
    unsigned int r = (x + 0x7fffu + ((x >> 16) & 1u)) >> 16;   // RNE
    return (unsigned short)r;
}

// ---------------------------------------------------------------------------
// edge decode; bin layout: [0,NS) js | [NS,NS+NJ) sj | [NS+NJ,NBINS) ss+loops
// ---------------------------------------------------------------------------
__device__ inline void edge_decode(int e, const int* js_src, const int* js_dst,
                                   const int* sj_src, const int* sj_dst,
                                   const int* ss_src, const int* ss_dst,
                                   int& src, int& bin) {
    if (e < E_JS) { src = js_src[e]; bin = js_dst[e]; }
    else if (e < E_JS + E_SJ) { int i = e - E_JS; src = sj_src[i]; bin = NS + sj_dst[i]; }
    else if (e < E_JS + E_SJ + E_SS) { int i = e - E_JS - E_SJ; src = ss_src[i]; bin = NS + NJ + ss_dst[i]; }
    else { int i = e - E_JS - E_SJ - E_SS; src = i; bin = NS + NJ + i; }
}

// ---------------------------------------------------------------------------
// D1 k_prep: castT [0,480) | wa [480,492) | qvec [492] | hist [493,493+512)
// bcnt zeroed by hipMemsetAsync before this dispatch.
// ---------------------------------------------------------------------------
struct CastT { const float* src; unsigned short* dst; int K; int N; };
struct PrepArgs {
    CastT m[CAST_MATS];
    const float* Ws; const float* as_; const float* Wd; const float* ad_;
    float* wsa; float* wda; int* bcnt;
    const float* query; const float* Wq; const float* bq; float* qv;
    const int* js_src; const int* js_dst;
    const int* sj_src; const int* sj_dst;
    const int* ss_src; const int* ss_dst;
};

__global__ __launch_bounds__(256) void k_prep(PrepArgs A) {
    __shared__ float ldt[32][33];
    __shared__ int lh[NBUK];
    int b = blockIdx.x;
    if (b < PREP_CAST) {
        int mi = b / CAST_BPM, bx = b % CAST_BPM;
        CastT cm = A.m[mi];
        int tilesN = cm.N >> 5;
        int total = (cm.K >> 5) * tilesN;
        if (bx >= total) return;
        int tk = bx / tilesN, tn = bx % tilesN;
        int k0 = tk * 32, n0 = tn * 32;
        int col = threadIdx.x & 31;
        int row0 = threadIdx.x >> 5;
#pragma unroll
        for (int r = 0; r < 4; ++r) {
            int kk = row0 + r * 8;
            ldt[kk][col] = cm.src[(size_t)(k0 + kk) * cm.N + n0 + col];
        }
        __syncthreads();
#pragma unroll
        for (int r = 0; r < 4; ++r) {
            int nn = row0 + r * 8;
            cm.dst[(size_t)(n0 + nn) * cm.K + k0 + col] = f2bf(ldt[col][nn]);
        }
    } else if (b < PREP_WA) {
        int id = (b - PREP_CAST) * 256 + threadIdx.x;
        if (id >= 2 * 1536) return;
        int which = id / 1536;
        int r = id % 1536;
        int lr = r / 256;
        int kh = r % 256;
        int k = kh / 2, h = kh % 2;
        const float* W = which ? A.Wd : A.Ws;
        const float* a = which ? A.ad_ : A.as_;
        const float* wrow = W + ((size_t)(lr * 128 + k)) * 256 + h * 128;
        const float* arow = a + (size_t)(lr * 2 + h) * 128;
        float acc = 0.f;
        for (int c2 = 0; c2 < 128; ++c2) acc += wrow[c2] * arow[c2];
        (which ? A.wda : A.wsa)[lr * 256 + k * 2 + h] = acc;
    } else if (b == PREP_QV) {
        int c = threadIdx.x;
        if (c < 128) {
            float acc = A.bq[c];
            for (int k = 0; k < SBERT; ++k) acc += A.query[k] * A.Wq[(size_t)k * 128 + c];
            A.qv[c] = acc;
        }
    } else {
        int t = threadIdx.x;
        for (int i = t; i < NBUK; i += 256) lh[i] = 0;
        __syncthreads();
        int hb = b - PREP_HIST;
        for (int e = hb * 256 + t; e < ETOT; e += HIST_NB * 256) {
            int src, bin;
            edge_decode(e, A.js_src, A.js_dst, A.sj_src, A.sj_dst, A.ss_src, A.ss_dst, src, bin);
            atomicAdd(&lh[bin >> 6], 1);
        }
        __syncthreads();
        for (int i = t; i < NBUK; i += 256) {
            int v = lh[i];
            if (v) atomicAdd(&A.bcnt[i], v);
        }
    }
}

// ---------------------------------------------------------------------------
// MFMA GEMM body. BM=64, 4 waves x (16m x 128n).
// EPI: 0 none->bf16, 1 +bias->fp32+scores, 2 +bias,relu->bf16, 3 +bias,LN,relu->bf16
// Optional alpha epilogue (aMode pairs; requires N==128, n0==0).
// ---------------------------------------------------------------------------
struct GJob {
    const void* X; const unsigned short* Wt;
    const float* bias; const float* gamma; const float* beta;
    void* Y; int M; int K; int N; int ldY; int srcf32;
    const float* qv; float* sc;
    int aMode = 0;
    const float* wav0 = nullptr; const float* wav1 = nullptr;
    const float* wav2 = nullptr; const float* wav3 = nullptr;
    float* aOut = nullptr; int aStride = 0;
};
struct GPair { GJob a; GJob b; int blocksA; };

template <int EPI>
__device__ void mgemm_body(const GPair& P, int bx, int by) {
    int mb = bx;
    GJob g = (mb < P.blocksA) ? P.a : P.b;
    if (mb >= P.blocksA) mb -= P.blocksA;
    const int n0 = by * 128;
    if (n0 >= g.N) return;
    const int row0 = mb * 64;

    __shared__ __align__(16) unsigned short Al[64][40];
    __shared__ __align__(16) unsigned short Bl[128][40];
    const int t = threadIdx.x;
    const int wave = t >> 6, lane = t & 63;
    const int q = lane >> 4, c = lane & 15;
    const int K = g.K;

    f4_t acc[8];
#pragma unroll
    for (int nt = 0; nt < 8; ++nt) acc[nt] = (f4_t){0.f, 0.f, 0.f, 0.f};

    for (int k0 = 0; k0 < K; k0 += 32) {
#pragma unroll
        for (int it = 0; it < 3; ++it) {
            int idx = t + it * 256;
            int r = idx >> 2, cc = (idx & 3) * 8;
            if (r < 64) {
                int gr = row0 + r;
                if (g.srcf32) {
                    ushort4 lo = make_ushort4(0, 0, 0, 0), hi = lo;
                    if (gr < g.M) {
                        const float* Xf = (const float*)g.X;
                        const float* p = &Xf[(size_t)gr * K + k0 + cc];
                        float4 f0 = *(const float4*)p;
                        float4 f1 = *(const float4*)(p + 4);
                        lo = make_ushort4(f2bf(f0.x), f2bf(f0.y), f2bf(f0.z), f2bf(f0.w));
                        hi = make_ushort4(f2bf(f1.x), f2bf(f1.y), f2bf(f1.z), f2bf(f1.w));
                    }
                    *(ushort4*)&Al[r][cc] = lo;
                    *(ushort4*)&Al[r][cc + 4] = hi;
                } else {
                    const unsigned short* Xb = (const unsigned short*)g.X;
                    uint4 va = (gr < g.M) ? *(const uint4*)&Xb[(size_t)gr * K + k0 + cc]
                                          : make_uint4(0u, 0u, 0u, 0u);
                    *(uint4*)&Al[r][cc] = va;
                }
            } else {
                int br = r - 64;
                *(uint4*)&Bl[br][cc] = *(const uint4*)&g.Wt[(size_t)(n0 + br) * K + k0 + cc];
            }
        }
        __syncthreads();
        bf8_t af = *(const bf8_t*)&Al[wave * 16 + c][q * 8];
#pragma unroll
        for (int nt = 0; nt < 8; ++nt) {
            bf8_t bfr = *(const bf8_t*)&Bl[nt * 16 + c][q * 8];
            acc[nt] = __builtin_amdgcn_mfma_f32_16x16x32_bf16(af, bfr, acc[nt], 0, 0, 0);
        }
        __syncthreads();
    }

    float bcol[8], gcol[8], becol[8], qcol[8];
#pragma unroll
    for (int nt = 0; nt < 8; ++nt) {
        bcol[nt] = (EPI >= 1) ? g.bias[n0 + nt * 16 + c] : 0.f;
        if constexpr (EPI == 3) {
            gcol[nt] = g.gamma[nt * 16 + c];
            becol[nt] = g.beta[nt * 16 + c];
        }
        if constexpr (EPI == 1) qcol[nt] = g.qv[n0 + nt * 16 + c];
    }

#pragma unroll
    for (int r = 0; r < 4; ++r) {
        int grow = row0 + wave * 16 + q * 4 + r;
        float v[8];
#pragma unroll
        for (int nt = 0; nt < 8; ++nt) v[nt] = acc[nt][r] + bcol[nt];
        if constexpr (EPI == 3) {
            float s = 0.f, ss = 0.f;
#pragma unroll
            for (int nt = 0; nt < 8; ++nt) { s += v[nt]; ss += v[nt] * v[nt]; }
#pragma unroll
            for (int m = 8; m >= 1; m >>= 1) {
                s += __shfl_xor(s, m, 64);
                ss += __shfl_xor(ss, m, 64);
            }
            float mu = s * (1.f / 128.f);
            float var = ss * (1.f / 128.f) - mu * mu;
            float rs = rsqrtf(var + 1e-5f);
#pragma unroll
            for (int nt = 0; nt < 8; ++nt)
                v[nt] = fmaxf((v[nt] - mu) * rs * gcol[nt] + becol[nt], 0.f);
        } else if constexpr (EPI == 2) {
#pragma unroll
            for (int nt = 0; nt < 8; ++nt) v[nt] = fmaxf(v[nt], 0.f);
        }
        if constexpr (EPI == 1) {
            float part = 0.f;
#pragma unroll
            for (int nt = 0; nt < 8; ++nt) part += v[nt] * qcol[nt];
#pragma unroll
            for (int m = 8; m >= 1; m >>= 1) part += __shfl_xor(part, m, 64);
            if (c == 0 && grow < g.M) g.sc[grow] = part;
        }
        if (g.aMode > 0) {
            float pa[8];
#pragma unroll
            for (int i = 0; i < 8; ++i) pa[i] = 0.f;
#pragma unroll
            for (int nt = 0; nt < 8; ++nt) {
                int col = nt * 16 + c;
                float2 w0 = *(const float2*)&g.wav0[col * 2];
                pa[0] += v[nt] * w0.x; pa[1] += v[nt] * w0.y;
                if (g.aMode > 1) {
                    float2 w1 = *(const float2*)&g.wav1[col * 2];
                    pa[2] += v[nt] * w1.x; pa[3] += v[nt] * w1.y;
                }
                if (g.aMode > 2) {
                    float2 w2 = *(const float2*)&g.wav2[col * 2];
                    float2 w3 = *(const float2*)&g.wav3[col * 2];
                    pa[4] += v[nt] * w2.x; pa[5] += v[nt] * w2.y;
                    pa[6] += v[nt] * w3.x; pa[7] += v[nt] * w3.y;
                }
            }
#pragma unroll
            for (int m = 8; m >= 1; m >>= 1) {
                pa[0] += __shfl_xor(pa[0], m, 64); pa[1] += __shfl_xor(pa[1], m, 64);
                pa[2] += __shfl_xor(pa[2], m, 64); pa[3] += __shfl_xor(pa[3], m, 64);
                pa[4] += __shfl_xor(pa[4], m, 64); pa[5] += __shfl_xor(pa[5], m, 64);
                pa[6] += __shfl_xor(pa[6], m, 64); pa[7] += __shfl_xor(pa[7], m, 64);
            }
            if (c == 0 && grow < g.M) {
                float* ao = &g.aOut[(size_t)grow * g.aStride];
                ao[0] = pa[0]; ao[1] = pa[1];
                if (g.aMode > 1) { ao[2] = pa[2]; ao[3] = pa[3]; }
                if (g.aMode > 2) { ao[4] = pa[4]; ao[5] = pa[5]; ao[6] = pa[6]; ao[7] = pa[7]; }
            }
        }
        if (grow < g.M) {
            if constexpr (EPI == 1) {
                float* Y = (float*)g.Y;
#pragma unroll
                for (int nt = 0; nt < 8; ++nt)
                    Y[(size_t)grow * g.ldY + n0 + nt * 16 + c] = v[nt];
            } else {
                unsigned short* Y = (unsigned short*)g.Y;
#pragma unroll
                for (int nt = 0; nt < 8; ++nt)
                    Y[(size_t)grow * g.ldY + n0 + nt * 16 + c] = f2bf(v[nt]);
            }
        }
    }
}

template <int EPI>
__global__ __launch_bounds__(256) void k_mgemm(GPair P) {
    mgemm_body<EPI>(P, blockIdx.x, blockIdx.y);
}

// ---------------------------------------------------------------------------
// D2: lin0 (LN+relu, alpha-l0 fused) + bucket scan (last block)
// ---------------------------------------------------------------------------
__global__ __launch_bounds__(256) void k_lin0_scan(
    GPair P, int gemmBlocks,
    const int* __restrict__ bcnt, int* __restrict__ bukoff, int* __restrict__ bukcur) {
    if (blockIdx.x < (unsigned)gemmBlocks) {
        mgemm_body<3>(P, blockIdx.x, 0);
        return;
    }
    __shared__ int sd[256];
    int t = threadIdx.x;
    int i0 = t * 4;
    int v0 = (i0 < NBUK) ? bcnt[i0] : 0;
    int v1 = (i0 + 1 < NBUK) ? bcnt[i0 + 1] : 0;
    int v2 = (i0 + 2 < NBUK) ? bcnt[i0 + 2] : 0;
    int v3 = (i0 + 3 < NBUK) ? bcnt[i0 + 3] : 0;
    int csum = v0 + v1 + v2 + v3;
    sd[t] = csum;
    __syncthreads();
    for (int off = 1; off < 256; off <<= 1) {
        int tmp = (t >= off) ? sd[t - off] : 0;
        __syncthreads();
        sd[t] += tmp;
        __syncthreads();
    }
    int excl = sd[t] - csum;
    int p0 = excl, p1 = excl + v0, p2 = excl + v0 + v1, p3 = excl + v0 + v1 + v2;
    if (i0 < NBUK) { bukoff[i0] = p0; bukcur[i0] = p0; }
    if (i0 + 1 < NBUK) { bukoff[i0 + 1] = p1; bukcur[i0 + 1] = p1; }
    if (i0 + 2 < NBUK) { bukoff[i0 + 2] = p2; bukcur[i0 + 2] = p2; }
    if (i0 + 3 < NBUK) { bukoff[i0 + 3] = p3; bukcur[i0 + 3] = p3; }
    if (t == 0) bukoff[NBUK] = ETOT;
}

// ---------------------------------------------------------------------------
// D3: scatter pairs + proj GEMM l0 (merged)
// ---------------------------------------------------------------------------
__global__ __launch_bounds__(256) void k_scatter_proj(
    GPair P, int gemmBlocks,
    const int* __restrict__ js_src, const int* __restrict__ js_dst,
    const int* __restrict__ sj_src, const int* __restrict__ sj_dst,
    const int* __restrict__ ss_src, const int* __restrict__ ss_dst,
    int* __restrict__ bukcur, uint2* __restrict__ pairs) {
    if (blockIdx.x < (unsigned)gemmBlocks) {
        mgemm_body<0>(P, blockIdx.x, blockIdx.y);
        return;
    }
    if (blockIdx.y != 0) return;
    __shared__ int lh[NBUK];
    __shared__ int lbase[NBUK];
    int t = threadIdx.x;
    int sb = blockIdx.x - gemmBlocks;
    const int CH = (ETOT + SCAT_NB - 1) / SCAT_NB;
    const int beg = sb * CH;
    const int endi = (beg + CH < ETOT) ? beg + CH : ETOT;
    for (int i = t; i < NBUK; i += 256) lh[i] = 0;
    __syncthreads();
    for (int e = beg + t; e < endi; e += 256) {
        int src, bin;
        edge_decode(e, js_src, js_dst, sj_src, sj_dst, ss_src, ss_dst, src, bin);
        atomicAdd(&lh[bin >> 6], 1);
    }
    __syncthreads();
    for (int i = t; i < NBUK; i += 256) {
        int v = lh[i];
        lbase[i] = v ? atomicAdd(&bukcur[i], v) : 0;
    }
    __syncthreads();
    for (int i = t; i < NBUK; i += 256) lh[i] = 0;
    __syncthreads();
    for (int e = beg + t; e < endi; e += 256) {
        int src, bin;
        edge_decode(e, js_src, js_dst, sj_src, sj_dst, ss_src, ss_dst, src, bin);
        int bu = bin >> 6;
        int pos = lbase[bu] + atomicAdd(&lh[bu], 1);
        pairs[pos] = make_uint2((unsigned)src, (unsigned)bin);
    }
}

// ---------------------------------------------------------------------------
// D4: finalize — one block per bucket, dense contiguous esrc writes
// ---------------------------------------------------------------------------
__global__ __launch_bounds__(256) void k_finalize(
    const uint2* __restrict__ pairs, const int* __restrict__ bukoff,
    int* __restrict__ offs, int* __restrict__ esrc) {
    int b = blockIdx.x, t = threadIdx.x;
    int base = bukoff[b], endi = bukoff[b + 1];
    __shared__ int cnt[64], excl[64], curs[64];
    if (t < 64) cnt[t] = 0;
    __syncthreads();
    for (int i = base + t; i < endi; i += 256)
        atomicAdd(&cnt[pairs[i].y & 63], 1);
    __syncthreads();
    if (t < 64) {
        int v = cnt[t];
        int inc = v;
#pragma unroll
        for (int off = 1; off < 64; off <<= 1) {
            int tmp = __shfl_up(inc, off, 64);
            if (t >= off) inc += tmp;
        }
        excl[t] = inc - v;
        curs[t] = inc - v;
    }
    __syncthreads();
    for (int i = base + t; i < endi; i += 256) {
        uint2 p = pairs[i];
        int lb = p.y & 63;
        int pos = atomicAdd(&curs[lb], 1);
        esrc[base + pos] = (int)p.x;
    }
    if (t < 64) {
        int bin = b * 64 + t;
        if (bin < NBINS) offs[bin] = base + excl[t];
    }
    if (b == 0 && t == 0) offs[NBINS] = ETOT;
}

// ---------------------------------------------------------------------------
// Gather v2: half-wave per edge. Lanes 0-31 take edge j, lanes 32-63 edge j+1;
// each lane covers 8 contiguous cols via one 16B load. Cross-half combine at
// the end via shfl_xor(32). bf16 unpack: lo = <<16, hi = &0xffff0000 (no shift).
// ---------------------------------------------------------------------------
__device__ inline void fmacc8(float p, uint4 u, float acc[8]) {
    acc[0] += p * __uint_as_float(u.x << 16);
    acc[1] += p * __uint_as_float(u.x & 0xffff0000u);
    acc[2] += p * __uint_as_float(u.y << 16);
    acc[3] += p * __uint_as_float(u.y & 0xffff0000u);
    acc[4] += p * __uint_as_float(u.z << 16);
    acc[5] += p * __uint_as_float(u.z & 0xffff0000u);
    acc[6] += p * __uint_as_float(u.w << 16);
    acc[7] += p * __uint_as_float(u.w & 0xffff0000u);
}

// one relation for one dst; acc[8]/den are per-lane partials (half-wave split)
__device__ inline void rel_run(
    const int* __restrict__ esrc, int beg, int cnt,
    const float* __restrict__ aSrc, int aShift, int aOff, float ad,
    const unsigned short* __restrict__ hs, int ldShift, int colBase, int half,
    float acc[8], float& den) {
    int n2 = cnt & ~1;
    int j = beg;
    for (; j + 4 <= beg + n2; j += 4) {        // 2 visits (4 edges), no predication
        int sA = esrc[j + half];
        int sB = esrc[j + 2 + half];
        uint4 uA = *(const uint4*)&hs[((size_t)sA << ldShift) + colBase];
        uint4 uB = *(const uint4*)&hs[((size_t)sB << ldShift) + colBase];
        float aA = aSrc[((size_t)sA << aShift) + aOff];
        float aB = aSrc[((size_t)sB << aShift) + aOff];
        float eA = aA + ad; eA = eA > 0.f ? eA : 0.2f * eA;
        float eB = aB + ad; eB = eB > 0.f ? eB : 0.2f * eB;
        float pA = __expf(eA), pB = __expf(eB);
        fmacc8(pA, uA, acc);
        fmacc8(pB, uB, acc);
        den += pA + pB;
    }
    for (; j < beg + n2; j += 2) {
        int s = esrc[j + half];
        uint4 u = *(const uint4*)&hs[((size_t)s << ldShift) + colBase];
        float a = aSrc[((size_t)s << aShift) + aOff];
        float e = a + ad; e = e > 0.f ? e : 0.2f * e;
        float p = __expf(e);
        fmacc8(p, u, acc);
        den += p;
    }
    if (cnt & 1) {
        if (!half) {                           // odd edge handled by half 0 only
            int s = esrc[beg + cnt - 1];
            uint4 u = *(const uint4*)&hs[((size_t)s << ldShift) + colBase];
            float a = aSrc[((size_t)s << aShift) + aOff];
            float e = a + ad; e = e > 0.f ? e : 0.2f * e;
            float p = __expf(e);
            fmacc8(p, u, acc);
            den += p;
        }
    }
}

__device__ inline void reduce_scale(float acc[8], float& den, float out[8], int add) {
    float d = den + __shfl_xor(den, 32, 64);
    float sc = 1.f / (d + 1e-16f);
#pragma unroll
    for (int i = 0; i < 8; ++i) {
        float t = acc[i] + __shfl_xor(acc[i], 32, 64);
        if (add) out[i] += t * sc; else out[i] = t * sc;
    }
}

__device__ inline void store8(unsigned short* dst, const float v[8]) {
    uint4 o;
    o.x = (unsigned)f2bf(v[0]) | ((unsigned)f2bf(v[1]) << 16);
    o.y = (unsigned)f2bf(v[2]) | ((unsigned)f2bf(v[3]) << 16);
    o.z = (unsigned)f2bf(v[4]) | ((unsigned)f2bf(v[5]) << 16);
    o.w = (unsigned)f2bf(v[6]) | ((unsigned)f2bf(v[7]) << 16);
    *(uint4*)dst = o;
}

__global__ __launch_bounds__(256) void k_gather_all(
    const int* __restrict__ offs, const int* __restrict__ esrc,
    const float* __restrict__ aJ, const float* __restrict__ aS,
    const unsigned short* __restrict__ hs1,              // js src rows, ld 256
    const unsigned short* __restrict__ hsss, int ssShift,    // ss src rows (pre-offset)
    const unsigned short* __restrict__ hsj, int sjShift,     // sj src rows
    const float* __restrict__ gb,
    unsigned short* __restrict__ oj, unsigned short* __restrict__ os,
    int jobOnly) {
    int wave = threadIdx.x >> 6, lane = threadIdx.x & 63;
    int idx = blockIdx.x * 4 + wave;
    int half = lane >> 5;
    int colBase = (lane & 31) * 8;        // 8 cols per lane
    int myH = (colBase >= 128) ? 1 : 0;

    float acc[8], den, out[8];
#pragma unroll
    for (int i = 0; i < 8; ++i) acc[i] = 0.f;
    den = 0.f;

    if (jobOnly) {
        if (idx >= NJ) return;
        int d = idx;
        int bb = NS + d;
        int beg = offs[bb], cnt = offs[bb + 1] - beg;
        float ad = aJ[(size_t)d * 4 + 2 + myH];
        rel_run(esrc, beg, cnt, aS, 3, 4 + myH, ad, hsj, sjShift, colBase, half, acc, den);
        reduce_scale(acc, den, out, 0);
        if (half == 0) {
            float4 b0 = *(const float4*)&gb[256 + colBase];
            float4 b1 = *(const float4*)&gb[256 + colBase + 4];
            out[0] += b0.x; out[1] += b0.y; out[2] += b0.z; out[3] += b0.w;
            out[4] += b1.x; out[5] += b1.y; out[6] += b1.z; out[7] += b1.w;
            store8(&oj[(size_t)d * 256 + colBase], out);
        }
        return;
    }
    if (idx < NS) {
        int d = idx;
        // js relation
        int beg = offs[d], cnt = offs[d + 1] - beg;
        float adA = aS[(size_t)d * 8 + 2 + myH];
        rel_run(esrc, beg, cnt, aJ, 2, myH, adA, hs1, 8, colBase, half, acc, den);
        reduce_scale(acc, den, out, 0);
        // ss relation
#pragma unroll
        for (int i = 0; i < 8; ++i) acc[i] = 0.f;
        den = 0.f;
        int bb = NS + NJ + d;
        int beg2 = offs[bb], cnt2 = offs[bb + 1] - beg2;
        float adB = aS[(size_t)d * 8 + 6 + myH];
        rel_run(esrc, beg2, cnt2, aS, 3, myH, adB, hsss, ssShift, colBase, half, acc, den);
        reduce_scale(acc, den, out, 1);
        if (half == 0) {
            float4 bA0 = *(const float4*)&gb[colBase];
            float4 bA1 = *(const float4*)&gb[colBase + 4];
            float4 bB0 = *(const float4*)&gb[512 + colBase];
            float4 bB1 = *(const float4*)&gb[512 + colBase + 4];
            out[0] += bA0.x + bB0.x; out[1] += bA0.y + bB0.y;
            out[2] += bA0.z + bB0.z; out[3] += bA0.w + bB0.w;
            out[4] += bA1.x + bB1.x; out[5] += bA1.y + bB1.y;
            out[6] += bA1.z + bB1.z; out[7] += bA1.w + bB1.w;
            store8(&os[(size_t)d * 256 + colBase], out);
        }
    } else if (idx < NS + NJ) {
        int d = idx - NS;
        int bb = NS + d;
        int beg = offs[bb], cnt = offs[bb + 1] - beg;
        float ad = aJ[(size_t)d * 4 + 2 + myH];
        rel_run(esrc, beg, cnt, aS, 3, 4 + myH, ad, hsj, sjShift, colBase, half, acc, den);
        reduce_scale(acc, den, out, 0);
        if (half == 0) {
            float4 b0 = *(const float4*)&gb[256 + colBase];
            float4 b1 = *(const float4*)&gb[256 + colBase + 4];
            out[0] += b0.x; out[1] += b0.y; out[2] += b0.z; out[3] += b0.w;
            out[4] += b1.x; out[5] += b1.y; out[6] += b1.z; out[7] += b1.w;
            store8(&oj[(size_t)d * 256 + colBase], out);
        }
    }
}

// ---------------------------------------------------------------------------
// Two-stage fused GEMM (unchanged from round 10)
// ---------------------------------------------------------------------------
struct FJob {
    const unsigned short* X; const unsigned short* Wt1; const float* bias1;
    int M; int K1;
    const float* wa; float* aOut; int aStride;
    const unsigned short* Wt2; const float* bias2; int N2;
    void* Y2; int ldY2; int y2f32;
    const float* qv; float* sc;
};
struct FPair { FJob a; FJob b; int blocksA; };

__global__ __launch_bounds__(256) void k_fused2(FPair P) {
    int mb = blockIdx.x;
    FJob g = (mb < P.blocksA) ? P.a : P.b;
    if (mb >= P.blocksA) mb -= P.blocksA;
    const int row0 = mb * 64;

    __shared__ __align__(16) unsigned short Al[64][40];
    __shared__ __align__(16) unsigned short Bl[128][40];
    __shared__ __align__(16) unsigned short Y1l[4][64][40];
    const int t = threadIdx.x;
    const int wave = t >> 6, lane = t & 63;
    const int q = lane >> 4, c = lane & 15;

    f4_t acc[8];
#pragma unroll
    for (int nt = 0; nt < 8; ++nt) acc[nt] = (f4_t){0.f, 0.f, 0.f, 0.f};

    for (int k0 = 0; k0 < g.K1; k0 += 32) {
#pragma unroll
        for (int it = 0; it < 3; ++it) {
            int idx = t + it * 256;
            int r = idx >> 2, cc = (idx & 3) * 8;
            if (r < 64) {
                int gr = row0 + r;
                uint4 va = (gr < g.M) ? *(const uint4*)&g.X[(size_t)gr * g.K1 + k0 + cc]
                                      : make_uint4(0u, 0u, 0u, 0u);
                *(uint4*)&Al[r][cc] = va;
            } else {
                int br = r - 64;
                *(uint4*)&Bl[br][cc] = *(const uint4*)&g.Wt1[(size_t)br * g.K1 + k0 + cc];
            }
        }
        __syncthreads();
        bf8_t af = *(const bf8_t*)&Al[wave * 16 + c][q * 8];
#pragma unroll
        for (int nt = 0; nt < 8; ++nt) {
            bf8_t bfr = *(const bf8_t*)&Bl[nt * 16 + c][q * 8];
            acc[nt] = __builtin_amdgcn_mfma_f32_16x16x32_bf16(af, bfr, acc[nt], 0, 0, 0);
        }
        __syncthreads();
    }

    float bcol[8];
#pragma unroll
    for (int nt = 0; nt < 8; ++nt) bcol[nt] = g.bias1[nt * 16 + c];
#pragma unroll
    for (int r = 0; r < 4; ++r) {
        int row = wave * 16 + q * 4 + r;
        int grow = row0 + row;
        float v[8];
#pragma unroll
        for (int nt = 0; nt < 8; ++nt) v[nt] = fmaxf(acc[nt][r] + bcol[nt], 0.f);
        if (g.wa) {
            float pa0 = 0.f, pa1 = 0.f;
#pragma unroll
            for (int nt = 0; nt < 8; ++nt) {
                float2 w0 = *(const float2*)&g.wa[(nt * 16 + c) * 2];
                pa0 += v[nt] * w0.x; pa1 += v[nt] * w0.y;
            }
#pragma unroll
            for (int m = 8; m >= 1; m >>= 1) {
                pa0 += __shfl_xor(pa0, m, 64);
                pa1 += __shfl_xor(pa1, m, 64);
            }
            if (c == 0 && grow < g.M) {
                g.aOut[(size_t)grow * g.aStride + 0] = pa0;
                g.aOut[(size_t)grow * g.aStride + 1] = pa1;
            }
        }
#pragma unroll
        for (int nt = 0; nt < 8; ++nt)
            Y1l[nt >> 1][row][(nt & 1) * 16 + c] = f2bf(v[nt]);
    }
    if (g.N2 == 0) return;
    __syncthreads();

    for (int n2 = 0; n2 < g.N2; n2 += 128) {
        f4_t acc2[8];
#pragma unroll
        for (int nt = 0; nt < 8; ++nt) acc2[nt] = (f4_t){0.f, 0.f, 0.f, 0.f};
        for (int k0 = 0; k0 < 128; k0 += 32) {
#pragma unroll
            for (int it = 0; it < 2; ++it) {
                int idx = t + it * 256;
                int br = idx >> 2, cc = (idx & 3) * 8;
                *(uint4*)&Bl[br][cc] = *(const uint4*)&g.Wt2[(size_t)(n2 + br) * 128 + k0 + cc];
            }
            __syncthreads();
            bf8_t af = *(const bf8_t*)&Y1l[k0 >> 5][wave * 16 + c][q * 8];
#pragma unroll
            for (int nt = 0; nt < 8; ++nt) {
                bf8_t bfr = *(const bf8_t*)&Bl[nt * 16 + c][q * 8];
                acc2[nt] = __builtin_amdgcn_mfma_f32_16x16x32_bf16(af, bfr, acc2[nt], 0, 0, 0);
            }
            __syncthreads();
        }
        float b2[8], qcol[8];
#pragma unroll
        for (int nt = 0; nt < 8; ++nt) {
            b2[nt] = g.bias2 ? g.bias2[n2 + nt * 16 + c] : 0.f;
            if (g.y2f32) qcol[nt] = g.qv[n2 + nt * 16 + c];
        }
#pragma unroll
        for (int r = 0; r < 4; ++r) {
            int grow = row0 + wave * 16 + q * 4 + r;
            float v[8];
#pragma unroll
            for (int nt = 0; nt < 8; ++nt) v[nt] = acc2[nt][r] + b2[nt];
            if (g.y2f32) {
                float part = 0.f;
#pragma unroll
                for (int nt = 0; nt < 8; ++nt) part += v[nt] * qcol[nt];
#pragma unroll
                for (int m = 8; m >= 1; m >>= 1) part += __shfl_xor(part, m, 64);
                if (c == 0 && grow < g.M) g.sc[grow] = part;
                if (grow < g.M) {
                    float* Y = (float*)g.Y2;
#pragma unroll
                    for (int nt = 0; nt < 8; ++nt)
                        Y[(size_t)grow * g.ldY2 + n2 + nt * 16 + c] = v[nt];
                }
            } else if (grow < g.M) {
                unsigned short* Y = (unsigned short*)g.Y2;
#pragma unroll
                for (int nt = 0; nt < 8; ++nt)
                    Y[(size_t)grow * g.ldY2 + n2 + nt * 16 + c] = f2bf(v[nt]);
            }
        }
    }
}

// ---------------------------------------------------------------------------
extern "C" void kernel_launch(void* const* d_in, const int* in_sizes, int n_in,
                              void* d_out, int out_size, void* d_ws, size_t ws_size,
                              hipStream_t stream) {
    const float* x_job   = (const float*)d_in[0];
    const float* x_skill = (const float*)d_in[1];
    const int* js_src = (const int*)d_in[2];
    const int* js_dst = (const int*)d_in[3];
    const int* sj_src = (const int*)d_in[4];
    const int* sj_dst = (const int*)d_in[5];
    const int* ss_src = (const int*)d_in[6];
    const int* ss_dst = (const int*)d_in[7];
    const float* query    = (const float*)d_in[8];
    const float* W0_job   = (const float*)d_in[9];
    const float* b0_job   = (const float*)d_in[10];
    const float* g0_job   = (const float*)d_in[11];
    const float* be0_job  = (const float*)d_in[12];
    const float* W0_skill = (const float*)d_in[13];
    const float* b0_skill = (const float*)d_in[14];
    const float* g0_skill = (const float*)d_in[15];
    const float* be0_skill= (const float*)d_in[16];
    const float* gat_Ws = (const float*)d_in[17];
    const float* gat_Wd = (const float*)d_in[18];
    const float* gat_as = (const float*)d_in[19];
    const float* gat_ad = (const float*)d_in[20];
    const float* gat_b  = (const float*)d_in[21];
    const float* inter_W = (const float*)d_in[22];
    const float* inter_b = (const float*)d_in[23];
    const float* Wjf = (const float*)d_in[24];
    const float* bjf = (const float*)d_in[25];
    const float* Wq  = (const float*)d_in[26];
    const float* bq  = (const float*)d_in[27];

    char* w = (char*)d_ws;
    auto alloc = [&](size_t bytes) -> void* {
        void* p = (void*)w;
        w += (bytes + 255) & ~(size_t)255;
        return p;
    };
    u16* xj  = (u16*)alloc((size_t)NJ * 128 * 2);
    u16* xs  = (u16*)alloc((size_t)NS * 128 * 2);
    u16* hs1 = (u16*)alloc((size_t)NJ * 256 * 2);
    u16* hs2 = (u16*)alloc((size_t)NS * 512 * 2);
    u16* hs3 = (u16*)alloc((size_t)NS * 256 * 2);
    u16* oj  = (u16*)alloc((size_t)NJ * 256 * 2);
    u16* os  = (u16*)alloc((size_t)NS * 256 * 2);
    u16* WtW0j = (u16*)alloc((size_t)SBERT * 128 * 2);
    u16* WtW0s = (u16*)alloc((size_t)SBERT * 128 * 2);
    u16* WtWs  = (u16*)alloc((size_t)6 * 128 * 256 * 2);
    u16* WtI   = (u16*)alloc((size_t)4 * 256 * 128 * 2);
    u16* WtJf  = (u16*)alloc((size_t)128 * 128 * 2);
    float* aJ = (float*)alloc((size_t)NJ * 4 * 4);
    float* aS = (float*)alloc((size_t)NS * 8 * 4);
    float* wsa = (float*)alloc(6 * 256 * 4);
    float* wda = (float*)alloc(6 * 256 * 4);
    int* bcnt   = (int*)alloc((size_t)NBUK * 4);
    int* bukoff = (int*)alloc((size_t)(NBUK + 1) * 4);
    int* bukcur = (int*)alloc((size_t)NBUK * 4);
    uint2* pairs = (uint2*)alloc((size_t)ETOT * 8);
    int* offs = (int*)alloc((size_t)(NBINS + 1) * 4);
    int* esrc = (int*)alloc((size_t)ETOT * 4);

    float* out = (float*)d_out;
    float* scores  = out;
    float* job_emb = out + NJ;
    float* qv      = out + NJ + (size_t)NJ * 128;

    const int mbJ = cdiv(NJ, 64);   // 469
    const int mbS = cdiv(NS, 64);   // 188
    const int gemmB = mbJ + mbS;    // 657

    // M0: zero bucket counters
    hipMemsetAsync(bcnt, 0, (size_t)NBUK * 4, stream);

    // D1: prep (weight transposes + wa + qvec + bucket hist)
    {
        PrepArgs A;
        A.m[0] = {W0_job, WtW0j, SBERT, 128};
        A.m[1] = {W0_skill, WtW0s, SBERT, 128};
        A.m[2] = {gat_Ws + (size_t)0 * 128 * 256, WtWs + (size_t)0 * 256 * 128, 128, 256};
        A.m[3] = {gat_Ws + (size_t)1 * 128 * 256, WtWs + (size_t)1 * 256 * 128, 128, 256};
        A.m[4] = {gat_Ws + (size_t)2 * 128 * 256, WtWs + (size_t)2 * 256 * 128, 128, 256};
        A.m[5] = {gat_Ws + (size_t)4 * 128 * 256, WtWs + (size_t)4 * 256 * 128, 128, 256};
        A.m[6] = {inter_W + (size_t)0 * 256 * 128, WtI + (size_t)0 * 128 * 256, 256, 128};
        A.m[7] = {inter_W + (size_t)1 * 256 * 128, WtI + (size_t)1 * 128 * 256, 256, 128};
        A.m[8] = {inter_W + (size_t)2 * 256 * 128, WtI + (size_t)2 * 128 * 256, 256, 128};
        A.m[9] = {Wjf, WtJf, 128, 128};
        A.Ws = gat_Ws; A.as_ = gat_as; A.Wd = gat_Wd; A.ad_ = gat_ad;
        A.wsa = wsa; A.wda = wda; A.bcnt = bcnt;
        A.query = query; A.Wq = Wq; A.bq = bq; A.qv = qv;
        A.js_src = js_src; A.js_dst = js_dst;
        A.sj_src = sj_src; A.sj_dst = sj_dst;
        A.ss_src = ss_src; A.ss_dst = ss_dst;
        k_prep<<<PREP_HIST + HIST_NB, 256, 0, stream>>>(A);
    }

    // D2: lin0 (LN+relu, fp32 src, alpha-l0 fused) + bucket scan
    {
        GPair P;
        P.a = {x_job, WtW0j, b0_job, g0_job, be0_job, xj, NJ, SBERT, 128, 128, 1,
               nullptr, nullptr, 2, wsa + 0, wda + 256, nullptr, nullptr, aJ, 4};
        P.b = {x_skill, WtW0s, b0_skill, g0_skill, be0_skill, xs, NS, SBERT, 128, 128, 1,
               nullptr, nullptr, 4, wsa + 2 * 256, wda + 0, wsa + 1 * 256, wda + 2 * 256, aS, 8};
        P.blocksA = mbJ;
        k_lin0_scan<<<dim3(gemmB + 1, 1), 256, 0, stream>>>(P, gemmB, bcnt, bukoff, bukcur);
    }

    // D3: scatter pairs + proj GEMM l0
    {
        GPair P;
        P.a = {xj, WtWs + (size_t)0 * 256 * 128, nullptr, nullptr, nullptr,
               hs1, NJ, 128, 256, 256, 0, nullptr, nullptr};
        P.b = {xs, WtWs + (size_t)1 * 256 * 128, nullptr, nullptr, nullptr,
               hs2, NS, 128, 512, 512, 0, nullptr, nullptr};
        P.blocksA = mbJ;
        k_scatter_proj<<<dim3(gemmB + SCAT_NB, 4), 256, 0, stream>>>(
            P, gemmB, js_src, js_dst, sj_src, sj_dst, ss_src, ss_dst, bukcur, pairs);
    }

    // D4: finalize CSR
    k_finalize<<<NBUK, 256, 0, stream>>>(pairs, bukoff, offs, esrc);

    // D5: gather l0 (full; js ld=256 shift 8, ss/sj ld=512 shift 9)
    k_gather_all<<<cdiv(NS + NJ, 4), 256, 0, stream>>>(
        offs, esrc, aJ, aS, hs1, hs2 + 256, 9, hs2, 9, gat_b, oj, os, 0);

    // D6: fused inter-l0. Job: relu GEMM -> aJ-l1 only. Skill: + stage2 -> hs3.
    {
        FPair P;
        P.a = {oj, WtI + (size_t)0 * 128 * 256, inter_b + 0, NJ, 256,
               wda + (size_t)4 * 256, aJ + 2, 4,
               nullptr, nullptr, 0, nullptr, 0, 0, nullptr, nullptr};
        P.b = {os, WtI + (size_t)1 * 128 * 256, inter_b + 128, NS, 256,
               wsa + (size_t)4 * 256, aS + 4, 8,
               WtWs + (size_t)4 * 256 * 128, nullptr, 256, hs3, 256, 0, nullptr, nullptr};
        P.blocksA = mbJ;
        k_fused2<<<dim3(gemmB, 1), 256, 0, stream>>>(P);
    }

    // D7: gather l1 (job dsts only; sj from hs3, ld=256 shift 8)
    k_gather_all<<<cdiv(NJ, 4), 256, 0, stream>>>(
        offs, esrc, aJ, aS, nullptr, nullptr, 8, hs3, 8,
        gat_b + (size_t)3 * 256, oj, nullptr, 1);

    // D8: fused inter-l1 + final projection + scores
    {
        FPair P;
        P.a = {oj, WtI + (size_t)2 * 128 * 256, inter_b + 2 * 128, NJ, 256,
               nullptr, nullptr, 0,
               WtJf, bjf, 128, job_emb, 128, 1, qv, scores};
        P.b = P.a;
        P.blocksA = mbJ;
        k_fused2<<<dim3(mbJ, 1), 256, 0, stream>>>(P);
    }
}